// Round 1
// baseline (1189.410 us; speedup 1.0000x reference)
//
#include <hip/hip_runtime.h>

#define IN_DIM 768
#define HID 256
#define OUT_DIM 128
#define NHEAD 8
#define NREL 6
#define RD 64
#define CH1 256
#define CH2 512

static __device__ __forceinline__ float leaky(float x) { return x > 0.f ? x : 0.2f * x; }

// ---------------- CSR build ----------------
__global__ void count_kernel(const int* __restrict__ dst0, const int* __restrict__ ety,
                             int* __restrict__ deg, int* __restrict__ relcnt, int E) {
    int e = blockIdx.x * blockDim.x + threadIdx.x;
    if (e >= E) return;
    int d = dst0[e];
    atomicAdd(&deg[d], 1);
    atomicAdd(&relcnt[d * NREL + ety[e]], 1);
}

__global__ void scan_kernel(const int* __restrict__ deg, int* __restrict__ rowptr, int n) {
    __shared__ int sh[1024];
    __shared__ int s_running;
    int t = threadIdx.x;
    if (t == 0) s_running = 0;
    __syncthreads();
    for (int base = 0; base < n; base += 1024) {
        int v = (base + t < n) ? deg[base + t] : 0;
        sh[t] = v;
        __syncthreads();
        for (int off = 1; off < 1024; off <<= 1) {
            int add = (t >= off) ? sh[t - off] : 0;
            __syncthreads();
            sh[t] += add;
            __syncthreads();
        }
        int incl = sh[t];
        if (base + t < n) rowptr[base + t] = s_running + incl - v;
        int total = sh[1023];
        __syncthreads();
        if (t == 0) s_running += total;
        __syncthreads();
    }
    if (t == 0) rowptr[n] = s_running;
}

__global__ void scatter_kernel(const int* __restrict__ src0, const int* __restrict__ dst0,
                               const int* __restrict__ ety, const int* __restrict__ rowptr,
                               int* __restrict__ fill, int* __restrict__ src_srt,
                               int* __restrict__ ty_srt, int E) {
    int e = blockIdx.x * blockDim.x + threadIdx.x;
    if (e >= E) return;
    int d = dst0[e];
    int pos = rowptr[d] + atomicAdd(&fill[d], 1);
    src_srt[pos] = src0[e];
    ty_srt[pos] = ety[e];
}

// rel_alpha[r][h] = sum_c (rel_emb[r] @ We1)[h*32+c] * att_e1[h][c]
__global__ void rel_alpha_kernel(const float* __restrict__ rel_emb, const float* __restrict__ We1,
                                 const float* __restrict__ att_e1, float* __restrict__ rel_alpha) {
    int t = threadIdx.x;
    if (t >= NREL * NHEAD) return;
    int r = t / NHEAD, h = t % NHEAD;
    float acc = 0.f;
    for (int c = 0; c < HID / NHEAD; c++) {
        float v = 0.f;
        for (int k = 0; k < RD; k++) v += rel_emb[r * RD + k] * We1[k * HID + h * 32 + c];
        acc += v * att_e1[h * 32 + c];
    }
    rel_alpha[r * NHEAD + h] = acc;
}

// ---------------- generic fp32 tiled GEMM: C[M,N] = A[M,K] @ B[K,N] ----------------
// BM=BN=64, BK=16, 256 threads, 4x4 micro-tile. N,K multiples of 64/16.
__global__ void __launch_bounds__(256) gemm_kernel(const float* __restrict__ A,
                                                   const float* __restrict__ B,
                                                   float* __restrict__ C, int M, int K, int N) {
    __shared__ float As[64][17];
    __shared__ float Bs[16][65];
    int t = threadIdx.x;
    int tx = t & 15, ty = t >> 4;
    int row0 = blockIdx.x * 64, col0 = blockIdx.y * 64;
    float c[4][4] = {};
    for (int k0 = 0; k0 < K; k0 += 16) {
        for (int u = t; u < 64 * 16; u += 256) {
            int r = u >> 4, cc = u & 15;
            int gr = row0 + r;
            As[r][cc] = (gr < M) ? A[(size_t)gr * K + k0 + cc] : 0.f;
        }
        for (int u = t; u < 16 * 64; u += 256) {
            int r = u >> 6, cc = u & 63;
            Bs[r][cc] = B[(size_t)(k0 + r) * N + col0 + cc];
        }
        __syncthreads();
#pragma unroll
        for (int kk = 0; kk < 16; kk++) {
            float a[4], b[4];
#pragma unroll
            for (int m = 0; m < 4; m++) a[m] = As[ty * 4 + m][kk];
#pragma unroll
            for (int n = 0; n < 4; n++) b[n] = Bs[kk][tx * 4 + n];
#pragma unroll
            for (int m = 0; m < 4; m++)
#pragma unroll
                for (int n = 0; n < 4; n++) c[m][n] += a[m] * b[n];
        }
        __syncthreads();
    }
    for (int m = 0; m < 4; m++) {
        int gr = row0 + ty * 4 + m;
        if (gr < M)
            for (int n = 0; n < 4; n++) C[(size_t)gr * N + col0 + tx * 4 + n] = c[m][n];
    }
}

// ---------------- per-node attention scalars, layer 1 ----------------
__global__ void __launch_bounds__(256) alpha1_kernel(const float* __restrict__ h1,
                                                     const float* __restrict__ att_s,
                                                     const float* __restrict__ att_d,
                                                     const int* __restrict__ relcnt,
                                                     const int* __restrict__ deg,
                                                     const float* __restrict__ rel_alpha,
                                                     float* __restrict__ als, float* __restrict__ ald,
                                                     float* __restrict__ selfa) {
    int i = blockIdx.x, t = threadIdx.x;
    int h = t >> 5, l = t & 31;
    float v = h1[(size_t)i * HID + t];
    float ps = v * att_s[t], pd = v * att_d[t];
    for (int o = 16; o > 0; o >>= 1) {
        ps += __shfl_xor(ps, o, 32);
        pd += __shfl_xor(pd, o, 32);
    }
    if (l == 0) {
        als[i * NHEAD + h] = ps;
        ald[i * NHEAD + h] = pd;
    }
    if (t < NHEAD) {
        float dv = fmaxf((float)deg[i], 1.0f);
        float acc = 0.f;
        for (int r = 0; r < NREL; r++) acc += (float)relcnt[i * NREL + r] * rel_alpha[r * NHEAD + t];
        selfa[i * NHEAD + t] = acc / dv;
    }
}

// ---------------- fused layer-1 aggregation + bias + LN + ELU ----------------
__global__ void __launch_bounds__(256) node_agg1(
    const float* __restrict__ h1, const float* __restrict__ als, const float* __restrict__ ald,
    const float* __restrict__ selfa, const float* __restrict__ rel_alpha,
    const int* __restrict__ rowptr, const int* __restrict__ src_srt, const int* __restrict__ ty_srt,
    const float* __restrict__ b1, const float* __restrict__ g1, const float* __restrict__ beta1,
    float* __restrict__ out) {
    int i = blockIdx.x, t = threadIdx.x;
    int h = t >> 5, l = t & 31;
    __shared__ float sh_alpha[CH1 * 8];
    __shared__ int sh_src[CH1];
    __shared__ float sh_rel[NREL * NHEAD];
    __shared__ float sh_ald[NHEAD];
    __shared__ float sh_m[NHEAD], sh_s[NHEAD], sh_f[NHEAD];
    __shared__ float sh_red[256];
    if (t < NREL * NHEAD) sh_rel[t] = rel_alpha[t];
    if (t < NHEAD) {
        float a_self = leaky(als[i * NHEAD + t] + ald[i * NHEAD + t] + selfa[i * NHEAD + t]);
        sh_m[t] = a_self;
        sh_s[t] = 1.0f;
        sh_ald[t] = ald[i * NHEAD + t];
    }
    __syncthreads();
    float acc = h1[(size_t)i * HID + t];  // self-loop contribution, weight exp(a_self - m)=1
    int base = rowptr[i];
    int deg = rowptr[i + 1] - base;
    for (int cs = 0; cs < deg; cs += CH1) {
        int c = min(CH1, deg - cs);
        for (int k = t; k < c * 8; k += 256) {
            int e = k >> 3, hh = k & 7;
            int sv = src_srt[base + cs + e];
            int tv = ty_srt[base + cs + e];
            float a = als[sv * NHEAD + hh] + sh_ald[hh] + sh_rel[tv * NHEAD + hh];
            sh_alpha[k] = leaky(a);
            if (hh == 0) sh_src[e] = sv;
        }
        __syncthreads();
        // per-head chunk max (32 threads per head)
        float cm = -1e30f;
        for (int e = l; e < c; e += 32) cm = fmaxf(cm, sh_alpha[e * 8 + h]);
        for (int o = 16; o > 0; o >>= 1) cm = fmaxf(cm, __shfl_xor(cm, o, 32));
        if (l == 0) {
            float mo = sh_m[h];
            float nm = fmaxf(mo, cm);
            sh_f[h] = __expf(mo - nm);
            sh_m[h] = nm;
        }
        __syncthreads();
        float nm = sh_m[h], f = sh_f[h];
        float csum = 0.f;
        for (int e = l; e < c; e += 32) {
            float w = __expf(sh_alpha[e * 8 + h] - nm);
            sh_alpha[e * 8 + h] = w;
            csum += w;
        }
        for (int o = 16; o > 0; o >>= 1) csum += __shfl_xor(csum, o, 32);
        if (l == 0) sh_s[h] = sh_s[h] * f + csum;
        acc *= f;
        __syncthreads();
        for (int e = 0; e < c; e++) acc += sh_alpha[e * 8 + h] * h1[(size_t)sh_src[e] * HID + t];
        __syncthreads();
    }
    float s = sh_s[h];
    acc = acc / (s + 1e-16f) + b1[t];
    // LayerNorm over 256 + ELU
    sh_red[t] = acc;
    __syncthreads();
    for (int o = 128; o > 0; o >>= 1) {
        if (t < o) sh_red[t] += sh_red[t + o];
        __syncthreads();
    }
    float mean = sh_red[0] * (1.f / 256.f);
    __syncthreads();
    float dd = acc - mean;
    sh_red[t] = dd * dd;
    __syncthreads();
    for (int o = 128; o > 0; o >>= 1) {
        if (t < o) sh_red[t] += sh_red[t + o];
        __syncthreads();
    }
    float var = sh_red[0] * (1.f / 256.f);
    float y = dd * rsqrtf(var + 1e-5f) * g1[t] + beta1[t];
    out[(size_t)i * HID + t] = y > 0.f ? y : __expf(y) - 1.f;
}

// ---------------- per-node attention scalars, layer 2 (1 head) ----------------
__global__ void __launch_bounds__(128) alpha2_kernel(const float* __restrict__ h2,
                                                     const float* __restrict__ att_s,
                                                     const float* __restrict__ att_d,
                                                     float* __restrict__ als, float* __restrict__ ald) {
    int i = blockIdx.x, t = threadIdx.x;
    float v = h2[(size_t)i * OUT_DIM + t];
    float ps = v * att_s[t], pd = v * att_d[t];
    for (int o = 32; o > 0; o >>= 1) {
        ps += __shfl_xor(ps, o, 64);
        pd += __shfl_xor(pd, o, 64);
    }
    __shared__ float r0[2], r1[2];
    if ((t & 63) == 0) {
        r0[t >> 6] = ps;
        r1[t >> 6] = pd;
    }
    __syncthreads();
    if (t == 0) {
        als[i] = r0[0] + r0[1];
        ald[i] = r1[0] + r1[1];
    }
}

// ---------------- fused layer-2 aggregation + bias + LN ----------------
__global__ void __launch_bounds__(128) node_agg2(const float* __restrict__ h2,
                                                 const float* __restrict__ als,
                                                 const float* __restrict__ ald,
                                                 const int* __restrict__ rowptr,
                                                 const int* __restrict__ src_srt,
                                                 const float* __restrict__ b2,
                                                 const float* __restrict__ g2,
                                                 const float* __restrict__ beta2,
                                                 float* __restrict__ out) {
    int i = blockIdx.x, t = threadIdx.x;
    __shared__ float sh_a[CH2];
    __shared__ int sh_src[CH2];
    __shared__ float sh_red[128];
    float aldi = ald[i];
    float aself = leaky(als[i] + aldi);
    float m = aself, s = 1.0f;
    float acc = h2[(size_t)i * OUT_DIM + t];
    int base = rowptr[i];
    int deg = rowptr[i + 1] - base;
    for (int cs = 0; cs < deg; cs += CH2) {
        int c = min(CH2, deg - cs);
        for (int k = t; k < c; k += 128) {
            int sv = src_srt[base + cs + k];
            sh_src[k] = sv;
            sh_a[k] = leaky(als[sv] + aldi);
        }
        __syncthreads();
        float cm = -1e30f;
        for (int e = t; e < c; e += 128) cm = fmaxf(cm, sh_a[e]);
        for (int o = 32; o > 0; o >>= 1) cm = fmaxf(cm, __shfl_xor(cm, o, 64));
        if ((t & 63) == 0) sh_red[t >> 6] = cm;
        __syncthreads();
        cm = fmaxf(sh_red[0], sh_red[1]);
        float newm = fmaxf(m, cm);
        float f = __expf(m - newm);
        float csum = 0.f;
        for (int k = t; k < c; k += 128) {
            float w = __expf(sh_a[k] - newm);
            sh_a[k] = w;
            csum += w;
        }
        for (int o = 32; o > 0; o >>= 1) csum += __shfl_xor(csum, o, 64);
        __syncthreads();  // protect sh_red reuse + make sh_a writes visible
        if ((t & 63) == 0) sh_red[t >> 6] = csum;
        __syncthreads();
        csum = sh_red[0] + sh_red[1];
        s = s * f + csum;
        m = newm;
        acc *= f;
        for (int e = 0; e < c; e++) acc += sh_a[e] * h2[(size_t)sh_src[e] * OUT_DIM + t];
        __syncthreads();
    }
    acc = acc / (s + 1e-16f) + b2[t];
    // LayerNorm over 128
    sh_red[t] = acc;
    __syncthreads();
    for (int o = 64; o > 0; o >>= 1) {
        if (t < o) sh_red[t] += sh_red[t + o];
        __syncthreads();
    }
    float mean = sh_red[0] * (1.f / 128.f);
    __syncthreads();
    float dd = acc - mean;
    sh_red[t] = dd * dd;
    __syncthreads();
    for (int o = 64; o > 0; o >>= 1) {
        if (t < o) sh_red[t] += sh_red[t + o];
        __syncthreads();
    }
    float var = sh_red[0] * (1.f / 128.f);
    out[(size_t)i * OUT_DIM + t] = dd * rsqrtf(var + 1e-5f) * g2[t] + beta2[t];
}

extern "C" void kernel_launch(void* const* d_in, const int* in_sizes, int n_in,
                              void* d_out, int out_size, void* d_ws, size_t ws_size,
                              hipStream_t stream) {
    const float* x = (const float*)d_in[0];
    const int* ei = (const int*)d_in[1];
    const int* ety = (const int*)d_in[2];
    const float* rel_emb = (const float*)d_in[3];
    const float* W1 = (const float*)d_in[4];
    const float* att_s1 = (const float*)d_in[5];
    const float* att_d1 = (const float*)d_in[6];
    const float* We1 = (const float*)d_in[7];
    const float* att_e1 = (const float*)d_in[8];
    const float* b1 = (const float*)d_in[9];
    const float* g1 = (const float*)d_in[10];
    const float* beta1 = (const float*)d_in[11];
    const float* W2 = (const float*)d_in[12];
    const float* att_s2 = (const float*)d_in[13];
    const float* att_d2 = (const float*)d_in[14];
    const float* b2 = (const float*)d_in[15];
    const float* g2 = (const float*)d_in[16];
    const float* beta2 = (const float*)d_in[17];

    int N = in_sizes[0] / IN_DIM;
    int E = in_sizes[1] / 2;
    const int* src0 = ei;
    const int* dst0 = ei + E;

    char* ws = (char*)d_ws;
    size_t off = 0;
    auto alloc = [&](size_t bytes) -> void* {
        off = (off + 255) & ~(size_t)255;
        void* p = ws + off;
        off += bytes;
        return p;
    };
    int* deg = (int*)alloc((size_t)N * 4);
    int* relcnt = (int*)alloc((size_t)N * NREL * 4);
    int* fill = (int*)alloc((size_t)N * 4);
    int* rowptr = (int*)alloc((size_t)(N + 1) * 4);
    int* src_srt = (int*)alloc((size_t)E * 4);
    int* ty_srt = (int*)alloc((size_t)E * 4);
    float* rel_alpha = (float*)alloc(NREL * NHEAD * 4);
    float* als1 = (float*)alloc((size_t)N * NHEAD * 4);
    float* ald1 = (float*)alloc((size_t)N * NHEAD * 4);
    float* selfa = (float*)alloc((size_t)N * NHEAD * 4);
    float* al2s = (float*)alloc((size_t)N * 4);
    float* al2d = (float*)alloc((size_t)N * 4);
    float* h1 = (float*)alloc((size_t)N * HID * 4);
    float* h1p = (float*)alloc((size_t)N * HID * 4);
    float* h2 = h1;  // h1 dead after node_agg1 -> reuse for layer-2 features

    hipMemsetAsync(deg, 0, (size_t)N * 4, stream);
    hipMemsetAsync(relcnt, 0, (size_t)N * NREL * 4, stream);
    hipMemsetAsync(fill, 0, (size_t)N * 4, stream);

    int eb = (E + 255) / 256;
    count_kernel<<<eb, 256, 0, stream>>>(dst0, ety, deg, relcnt, E);
    scan_kernel<<<1, 1024, 0, stream>>>(deg, rowptr, N);
    scatter_kernel<<<eb, 256, 0, stream>>>(src0, dst0, ety, rowptr, fill, src_srt, ty_srt, E);
    rel_alpha_kernel<<<1, 64, 0, stream>>>(rel_emb, We1, att_e1, rel_alpha);

    dim3 g1g((N + 63) / 64, HID / 64);
    gemm_kernel<<<g1g, 256, 0, stream>>>(x, W1, h1, N, IN_DIM, HID);
    alpha1_kernel<<<N, 256, 0, stream>>>(h1, att_s1, att_d1, relcnt, deg, rel_alpha, als1, ald1, selfa);
    node_agg1<<<N, 256, 0, stream>>>(h1, als1, ald1, selfa, rel_alpha, rowptr, src_srt, ty_srt,
                                     b1, g1, beta1, h1p);

    dim3 g2g((N + 63) / 64, OUT_DIM / 64);
    gemm_kernel<<<g2g, 256, 0, stream>>>(h1p, W2, h2, N, HID, OUT_DIM);
    alpha2_kernel<<<N, 128, 0, stream>>>(h2, att_s2, att_d2, al2s, al2d);
    node_agg2<<<N, 128, 0, stream>>>(h2, al2s, al2d, rowptr, src_srt, b2, g2, beta2, (float*)d_out);
}

// Round 2
// 693.208 us; speedup vs baseline: 1.7158x; 1.7158x over previous
//
#include <hip/hip_runtime.h>
#include <hip/hip_bf16.h>

#define IN_DIM 768
#define HID 256
#define OUT_DIM 128
#define NHEAD 8
#define NREL 6
#define RD 64
#define CH1 256
#define CH2 512

typedef unsigned short ushort_t;
typedef float f32x4 __attribute__((ext_vector_type(4)));
typedef __bf16 bf16x8 __attribute__((ext_vector_type(8)));
typedef unsigned short u16x8 __attribute__((ext_vector_type(8)));

static __device__ __forceinline__ float leaky(float x) { return x > 0.f ? x : 0.2f * x; }

static __device__ __forceinline__ ushort_t f2bf(float f) {
    union { __hip_bfloat16 h; ushort_t u; } c;
    c.h = __float2bfloat16(f);
    return c.u;
}

// ---------------- CSR build ----------------
__global__ void count_kernel(const int* __restrict__ dst0, const int* __restrict__ ety,
                             int* __restrict__ deg, int* __restrict__ relcnt, int E) {
    int e = blockIdx.x * blockDim.x + threadIdx.x;
    if (e >= E) return;
    int d = dst0[e];
    atomicAdd(&deg[d], 1);
    atomicAdd(&relcnt[d * NREL + ety[e]], 1);
}

__global__ void scan_kernel(const int* __restrict__ deg, int* __restrict__ rowptr, int n) {
    __shared__ int sh[1024];
    __shared__ int s_running;
    int t = threadIdx.x;
    if (t == 0) s_running = 0;
    __syncthreads();
    for (int base = 0; base < n; base += 1024) {
        int v = (base + t < n) ? deg[base + t] : 0;
        sh[t] = v;
        __syncthreads();
        for (int off = 1; off < 1024; off <<= 1) {
            int add = (t >= off) ? sh[t - off] : 0;
            __syncthreads();
            sh[t] += add;
            __syncthreads();
        }
        int incl = sh[t];
        if (base + t < n) rowptr[base + t] = s_running + incl - v;
        int total = sh[1023];
        __syncthreads();
        if (t == 0) s_running += total;
        __syncthreads();
    }
    if (t == 0) rowptr[n] = s_running;
}

__global__ void scatter_kernel(const int* __restrict__ src0, const int* __restrict__ dst0,
                               const int* __restrict__ ety, const int* __restrict__ rowptr,
                               int* __restrict__ fill, int* __restrict__ src_srt,
                               int* __restrict__ ty_srt, int E) {
    int e = blockIdx.x * blockDim.x + threadIdx.x;
    if (e >= E) return;
    int d = dst0[e];
    int pos = rowptr[d] + atomicAdd(&fill[d], 1);
    src_srt[pos] = src0[e];
    ty_srt[pos] = ety[e];
}

// rel_alpha[r][h] = sum_c (rel_emb[r] @ We1)[h*32+c] * att_e1[h][c]
__global__ void rel_alpha_kernel(const float* __restrict__ rel_emb, const float* __restrict__ We1,
                                 const float* __restrict__ att_e1, float* __restrict__ rel_alpha) {
    int t = threadIdx.x;
    if (t >= NREL * NHEAD) return;
    int r = t / NHEAD, h = t % NHEAD;
    float acc = 0.f;
    for (int c = 0; c < HID / NHEAD; c++) {
        float v = 0.f;
        for (int k = 0; k < RD; k++) v += rel_emb[r * RD + k] * We1[k * HID + h * 32 + c];
        acc += v * att_e1[h * 32 + c];
    }
    rel_alpha[r * NHEAD + h] = acc;
}

// W[K][Nc] fp32 -> Wt[Nc][K] bf16
__global__ void transpose_conv(const float* __restrict__ W, ushort_t* __restrict__ Wt,
                               int K, int Nc) {
    int i = blockIdx.x * 256 + threadIdx.x;
    if (i >= K * Nc) return;
    int k = i / Nc, n = i % Nc;
    Wt[n * K + k] = f2bf(W[i]);
}

// ---------------- MFMA bf16 GEMM: C[M,Nout] = A[M,K] @ Bt[Nout,K]^T ----------------
// 128x128 tile, BK=64, 4 waves, 4x4 16x16x32 fragments per wave.
// A either fp32 (converted during staging) or bf16 (pre-padded to tile multiple).
// LDS tiles padded: row stride 72 bf16 (144 B) -> fragment ds_read_b128 2-way max.
template <bool AF32>
__global__ void __launch_bounds__(256) gemm_mfma(const float* __restrict__ Af,
                                                 const ushort_t* __restrict__ Ab,
                                                 const ushort_t* __restrict__ Bt,
                                                 float* __restrict__ C,
                                                 int M, int K, int Nout) {
    __shared__ ushort_t sA[128 * 72];
    __shared__ ushort_t sB[128 * 72];
    int t = threadIdx.x;
    int w = t >> 6, l = t & 63;
    int m0 = blockIdx.x * 128;
    int n0 = blockIdx.y * 128;
    int wm = (w >> 1) * 64, wn = (w & 1) * 64;
    int r = t >> 1;       // staging row 0..127
    int hh = t & 1;       // 32-col half
    f32x4 acc[4][4] = {};
    for (int k0 = 0; k0 < K; k0 += 64) {
        // ---- stage A ----
        {
            u16x8 o[4];
            if (AF32) {
                float4 f[8];
                if (m0 + r < M) {
                    const float4* s4 = reinterpret_cast<const float4*>(
                        Af + (size_t)(m0 + r) * K + k0 + hh * 32);
#pragma unroll
                    for (int i = 0; i < 8; i++) f[i] = s4[i];
                } else {
#pragma unroll
                    for (int i = 0; i < 8; i++) f[i] = make_float4(0.f, 0.f, 0.f, 0.f);
                }
#pragma unroll
                for (int j = 0; j < 4; j++) {
                    o[j][0] = f2bf(f[2 * j].x);
                    o[j][1] = f2bf(f[2 * j].y);
                    o[j][2] = f2bf(f[2 * j].z);
                    o[j][3] = f2bf(f[2 * j].w);
                    o[j][4] = f2bf(f[2 * j + 1].x);
                    o[j][5] = f2bf(f[2 * j + 1].y);
                    o[j][6] = f2bf(f[2 * j + 1].z);
                    o[j][7] = f2bf(f[2 * j + 1].w);
                }
            } else {
                const u16x8* s8 = reinterpret_cast<const u16x8*>(
                    Ab + (size_t)(m0 + r) * K + k0 + hh * 32);
#pragma unroll
                for (int j = 0; j < 4; j++) o[j] = s8[j];
            }
#pragma unroll
            for (int j = 0; j < 4; j++)
                *reinterpret_cast<u16x8*>(&sA[r * 72 + hh * 32 + j * 8]) = o[j];
        }
        // ---- stage B ----
        {
            const u16x8* s8 = reinterpret_cast<const u16x8*>(
                Bt + (size_t)(n0 + r) * K + k0 + hh * 32);
#pragma unroll
            for (int j = 0; j < 4; j++)
                *reinterpret_cast<u16x8*>(&sB[r * 72 + hh * 32 + j * 8]) = s8[j];
        }
        __syncthreads();
#pragma unroll
        for (int ks = 0; ks < 2; ks++) {
            bf16x8 af[4], bf[4];
#pragma unroll
            for (int m = 0; m < 4; m++)
                af[m] = *reinterpret_cast<const bf16x8*>(
                    &sA[(wm + m * 16 + (l & 15)) * 72 + ks * 32 + (l >> 4) * 8]);
#pragma unroll
            for (int n = 0; n < 4; n++)
                bf[n] = *reinterpret_cast<const bf16x8*>(
                    &sB[(wn + n * 16 + (l & 15)) * 72 + ks * 32 + (l >> 4) * 8]);
#pragma unroll
            for (int m = 0; m < 4; m++)
#pragma unroll
                for (int n = 0; n < 4; n++)
                    acc[m][n] = __builtin_amdgcn_mfma_f32_16x16x32_bf16(af[m], bf[n], acc[m][n], 0, 0, 0);
        }
        __syncthreads();
    }
#pragma unroll
    for (int m = 0; m < 4; m++) {
#pragma unroll
        for (int rr = 0; rr < 4; rr++) {
            int row = m0 + wm + m * 16 + (l >> 4) * 4 + rr;
            if (row < M) {
#pragma unroll
                for (int n = 0; n < 4; n++)
                    C[(size_t)row * Nout + n0 + wn + n * 16 + (l & 15)] = acc[m][n][rr];
            }
        }
    }
}

// ---------------- per-node attention scalars, layer 1 ----------------
__global__ void __launch_bounds__(256) alpha1_kernel(const float* __restrict__ h1,
                                                     const float* __restrict__ att_s,
                                                     const float* __restrict__ att_d,
                                                     const int* __restrict__ relcnt,
                                                     const int* __restrict__ deg,
                                                     const float* __restrict__ rel_alpha,
                                                     float* __restrict__ als, float* __restrict__ ald,
                                                     float* __restrict__ selfa) {
    int i = blockIdx.x, t = threadIdx.x;
    int h = t >> 5, l = t & 31;
    float v = h1[(size_t)i * HID + t];
    float ps = v * att_s[t], pd = v * att_d[t];
    for (int o = 16; o > 0; o >>= 1) {
        ps += __shfl_xor(ps, o, 32);
        pd += __shfl_xor(pd, o, 32);
    }
    if (l == 0) {
        als[i * NHEAD + h] = ps;
        ald[i * NHEAD + h] = pd;
    }
    if (t < NHEAD) {
        float dv = fmaxf((float)deg[i], 1.0f);
        float acc = 0.f;
        for (int r = 0; r < NREL; r++) acc += (float)relcnt[i * NREL + r] * rel_alpha[r * NHEAD + t];
        selfa[i * NHEAD + t] = acc / dv;
    }
}

// ---------------- fused layer-1 aggregation + bias + LN + ELU (bf16 out) ----------------
__global__ void __launch_bounds__(256) node_agg1(
    const float* __restrict__ h1, const float* __restrict__ als, const float* __restrict__ ald,
    const float* __restrict__ selfa, const float* __restrict__ rel_alpha,
    const int* __restrict__ rowptr, const int* __restrict__ src_srt, const int* __restrict__ ty_srt,
    const float* __restrict__ b1, const float* __restrict__ g1, const float* __restrict__ beta1,
    ushort_t* __restrict__ out) {
    int i = blockIdx.x, t = threadIdx.x;
    int h = t >> 5, l = t & 31;
    __shared__ float sh_alpha[CH1 * 8];
    __shared__ int sh_src[CH1];
    __shared__ float sh_rel[NREL * NHEAD];
    __shared__ float sh_ald[NHEAD];
    __shared__ float sh_m[NHEAD], sh_s[NHEAD], sh_f[NHEAD];
    __shared__ float sh_red[256];
    if (t < NREL * NHEAD) sh_rel[t] = rel_alpha[t];
    if (t < NHEAD) {
        float a_self = leaky(als[i * NHEAD + t] + ald[i * NHEAD + t] + selfa[i * NHEAD + t]);
        sh_m[t] = a_self;
        sh_s[t] = 1.0f;
        sh_ald[t] = ald[i * NHEAD + t];
    }
    __syncthreads();
    float acc = h1[(size_t)i * HID + t];  // self-loop contribution, weight exp(a_self - m)=1
    int base = rowptr[i];
    int deg = rowptr[i + 1] - base;
    for (int cs = 0; cs < deg; cs += CH1) {
        int c = min(CH1, deg - cs);
        for (int k = t; k < c * 8; k += 256) {
            int e = k >> 3, hh = k & 7;
            int sv = src_srt[base + cs + e];
            int tv = ty_srt[base + cs + e];
            float a = als[sv * NHEAD + hh] + sh_ald[hh] + sh_rel[tv * NHEAD + hh];
            sh_alpha[k] = leaky(a);
            if (hh == 0) sh_src[e] = sv;
        }
        __syncthreads();
        float cm = -1e30f;
        for (int e = l; e < c; e += 32) cm = fmaxf(cm, sh_alpha[e * 8 + h]);
        for (int o = 16; o > 0; o >>= 1) cm = fmaxf(cm, __shfl_xor(cm, o, 32));
        if (l == 0) {
            float mo = sh_m[h];
            float nm = fmaxf(mo, cm);
            sh_f[h] = __expf(mo - nm);
            sh_m[h] = nm;
        }
        __syncthreads();
        float nm = sh_m[h], f = sh_f[h];
        float csum = 0.f;
        for (int e = l; e < c; e += 32) {
            float w = __expf(sh_alpha[e * 8 + h] - nm);
            sh_alpha[e * 8 + h] = w;
            csum += w;
        }
        for (int o = 16; o > 0; o >>= 1) csum += __shfl_xor(csum, o, 32);
        if (l == 0) sh_s[h] = sh_s[h] * f + csum;
        acc *= f;
        __syncthreads();
        for (int e = 0; e < c; e++) acc += sh_alpha[e * 8 + h] * h1[(size_t)sh_src[e] * HID + t];
        __syncthreads();
    }
    float s = sh_s[h];
    acc = acc / (s + 1e-16f) + b1[t];
    sh_red[t] = acc;
    __syncthreads();
    for (int o = 128; o > 0; o >>= 1) {
        if (t < o) sh_red[t] += sh_red[t + o];
        __syncthreads();
    }
    float mean = sh_red[0] * (1.f / 256.f);
    __syncthreads();
    float dd = acc - mean;
    sh_red[t] = dd * dd;
    __syncthreads();
    for (int o = 128; o > 0; o >>= 1) {
        if (t < o) sh_red[t] += sh_red[t + o];
        __syncthreads();
    }
    float var = sh_red[0] * (1.f / 256.f);
    float y = dd * rsqrtf(var + 1e-5f) * g1[t] + beta1[t];
    out[(size_t)i * HID + t] = f2bf(y > 0.f ? y : __expf(y) - 1.f);
}

// ---------------- per-node attention scalars, layer 2 (1 head) ----------------
__global__ void __launch_bounds__(128) alpha2_kernel(const float* __restrict__ h2,
                                                     const float* __restrict__ att_s,
                                                     const float* __restrict__ att_d,
                                                     float* __restrict__ als, float* __restrict__ ald) {
    int i = blockIdx.x, t = threadIdx.x;
    float v = h2[(size_t)i * OUT_DIM + t];
    float ps = v * att_s[t], pd = v * att_d[t];
    for (int o = 32; o > 0; o >>= 1) {
        ps += __shfl_xor(ps, o, 64);
        pd += __shfl_xor(pd, o, 64);
    }
    __shared__ float r0[2], r1[2];
    if ((t & 63) == 0) {
        r0[t >> 6] = ps;
        r1[t >> 6] = pd;
    }
    __syncthreads();
    if (t == 0) {
        als[i] = r0[0] + r0[1];
        ald[i] = r1[0] + r1[1];
    }
}

// ---------------- fused layer-2 aggregation + bias + LN ----------------
__global__ void __launch_bounds__(128) node_agg2(const float* __restrict__ h2,
                                                 const float* __restrict__ als,
                                                 const float* __restrict__ ald,
                                                 const int* __restrict__ rowptr,
                                                 const int* __restrict__ src_srt,
                                                 const float* __restrict__ b2,
                                                 const float* __restrict__ g2,
                                                 const float* __restrict__ beta2,
                                                 float* __restrict__ out) {
    int i = blockIdx.x, t = threadIdx.x;
    __shared__ float sh_a[CH2];
    __shared__ int sh_src[CH2];
    __shared__ float sh_red[128];
    float aldi = ald[i];
    float aself = leaky(als[i] + aldi);
    float m = aself, s = 1.0f;
    float acc = h2[(size_t)i * OUT_DIM + t];
    int base = rowptr[i];
    int deg = rowptr[i + 1] - base;
    for (int cs = 0; cs < deg; cs += CH2) {
        int c = min(CH2, deg - cs);
        for (int k = t; k < c; k += 128) {
            int sv = src_srt[base + cs + k];
            sh_src[k] = sv;
            sh_a[k] = leaky(als[sv] + aldi);
        }
        __syncthreads();
        float cm = -1e30f;
        for (int e = t; e < c; e += 128) cm = fmaxf(cm, sh_a[e]);
        for (int o = 32; o > 0; o >>= 1) cm = fmaxf(cm, __shfl_xor(cm, o, 64));
        if ((t & 63) == 0) sh_red[t >> 6] = cm;
        __syncthreads();
        cm = fmaxf(sh_red[0], sh_red[1]);
        float newm = fmaxf(m, cm);
        float f = __expf(m - newm);
        float csum = 0.f;
        for (int k = t; k < c; k += 128) {
            float w = __expf(sh_a[k] - newm);
            sh_a[k] = w;
            csum += w;
        }
        for (int o = 32; o > 0; o >>= 1) csum += __shfl_xor(csum, o, 64);
        __syncthreads();
        if ((t & 63) == 0) sh_red[t >> 6] = csum;
        __syncthreads();
        csum = sh_red[0] + sh_red[1];
        s = s * f + csum;
        m = newm;
        acc *= f;
        for (int e = 0; e < c; e++) acc += sh_a[e] * h2[(size_t)sh_src[e] * OUT_DIM + t];
        __syncthreads();
    }
    acc = acc / (s + 1e-16f) + b2[t];
    sh_red[t] = acc;
    __syncthreads();
    for (int o = 64; o > 0; o >>= 1) {
        if (t < o) sh_red[t] += sh_red[t + o];
        __syncthreads();
    }
    float mean = sh_red[0] * (1.f / 128.f);
    __syncthreads();
    float dd = acc - mean;
    sh_red[t] = dd * dd;
    __syncthreads();
    for (int o = 64; o > 0; o >>= 1) {
        if (t < o) sh_red[t] += sh_red[t + o];
        __syncthreads();
    }
    float var = sh_red[0] * (1.f / 128.f);
    out[(size_t)i * OUT_DIM + t] = dd * rsqrtf(var + 1e-5f) * g2[t] + beta2[t];
}

extern "C" void kernel_launch(void* const* d_in, const int* in_sizes, int n_in,
                              void* d_out, int out_size, void* d_ws, size_t ws_size,
                              hipStream_t stream) {
    const float* x = (const float*)d_in[0];
    const int* ei = (const int*)d_in[1];
    const int* ety = (const int*)d_in[2];
    const float* rel_emb = (const float*)d_in[3];
    const float* W1 = (const float*)d_in[4];
    const float* att_s1 = (const float*)d_in[5];
    const float* att_d1 = (const float*)d_in[6];
    const float* We1 = (const float*)d_in[7];
    const float* att_e1 = (const float*)d_in[8];
    const float* b1 = (const float*)d_in[9];
    const float* g1 = (const float*)d_in[10];
    const float* beta1 = (const float*)d_in[11];
    const float* W2 = (const float*)d_in[12];
    const float* att_s2 = (const float*)d_in[13];
    const float* att_d2 = (const float*)d_in[14];
    const float* b2 = (const float*)d_in[15];
    const float* g2 = (const float*)d_in[16];
    const float* beta2 = (const float*)d_in[17];

    int N = in_sizes[0] / IN_DIM;
    int E = in_sizes[1] / 2;
    int Mpad = ((N + 127) / 128) * 128;
    const int* src0 = ei;
    const int* dst0 = ei + E;

    char* ws = (char*)d_ws;
    size_t off = 0;
    auto alloc = [&](size_t bytes) -> void* {
        off = (off + 255) & ~(size_t)255;
        void* p = ws + off;
        off += bytes;
        return p;
    };
    int* deg = (int*)alloc((size_t)N * 4);
    int* relcnt = (int*)alloc((size_t)N * NREL * 4);
    int* fill = (int*)alloc((size_t)N * 4);
    int* rowptr = (int*)alloc((size_t)(N + 1) * 4);
    int* src_srt = (int*)alloc((size_t)E * 4);
    int* ty_srt = (int*)alloc((size_t)E * 4);
    float* rel_alpha = (float*)alloc(NREL * NHEAD * 4);
    float* als1 = (float*)alloc((size_t)N * NHEAD * 4);
    float* ald1 = (float*)alloc((size_t)N * NHEAD * 4);
    float* selfa = (float*)alloc((size_t)N * NHEAD * 4);
    float* al2s = (float*)alloc((size_t)N * 4);
    float* al2d = (float*)alloc((size_t)N * 4);
    ushort_t* W1t = (ushort_t*)alloc((size_t)HID * IN_DIM * 2);
    ushort_t* W2t = (ushort_t*)alloc((size_t)OUT_DIM * HID * 2);
    float* h1 = (float*)alloc((size_t)Mpad * HID * 4);
    ushort_t* h1pb = (ushort_t*)alloc((size_t)Mpad * HID * 2);
    float* h2 = h1;  // h1 dead after node_agg1 -> reuse for layer-2 features

    hipMemsetAsync(deg, 0, (size_t)N * 4, stream);
    hipMemsetAsync(relcnt, 0, (size_t)N * NREL * 4, stream);
    hipMemsetAsync(fill, 0, (size_t)N * 4, stream);

    int eb = (E + 255) / 256;
    count_kernel<<<eb, 256, 0, stream>>>(dst0, ety, deg, relcnt, E);
    scan_kernel<<<1, 1024, 0, stream>>>(deg, rowptr, N);
    scatter_kernel<<<eb, 256, 0, stream>>>(src0, dst0, ety, rowptr, fill, src_srt, ty_srt, E);
    rel_alpha_kernel<<<1, 64, 0, stream>>>(rel_emb, We1, att_e1, rel_alpha);
    transpose_conv<<<(IN_DIM * HID + 255) / 256, 256, 0, stream>>>(W1, W1t, IN_DIM, HID);
    transpose_conv<<<(HID * OUT_DIM + 255) / 256, 256, 0, stream>>>(W2, W2t, HID, OUT_DIM);

    dim3 g1g(Mpad / 128, HID / 128);
    gemm_mfma<true><<<g1g, 256, 0, stream>>>(x, (const ushort_t*)nullptr, W1t, h1, N, IN_DIM, HID);
    alpha1_kernel<<<N, 256, 0, stream>>>(h1, att_s1, att_d1, relcnt, deg, rel_alpha, als1, ald1, selfa);
    hipMemsetAsync(h1pb, 0, (size_t)Mpad * HID * 2, stream);
    node_agg1<<<N, 256, 0, stream>>>(h1, als1, ald1, selfa, rel_alpha, rowptr, src_srt, ty_srt,
                                     b1, g1, beta1, h1pb);

    dim3 g2g(Mpad / 128, OUT_DIM / 128);
    gemm_mfma<false><<<g2g, 256, 0, stream>>>((const float*)nullptr, h1pb, W2t, h2, N, HID, OUT_DIM);
    alpha2_kernel<<<N, 128, 0, stream>>>(h2, att_s2, att_d2, al2s, al2d);
    node_agg2<<<N, 128, 0, stream>>>(h2, al2s, al2d, rowptr, src_srt, b2, g2, beta2, (float*)d_out);
}

// Round 3
// 652.392 us; speedup vs baseline: 1.8232x; 1.0626x over previous
//
#include <hip/hip_runtime.h>
#include <hip/hip_bf16.h>

#define IN_DIM 768
#define HID 256
#define OUT_DIM 128
#define NHEAD 8
#define NREL 6
#define RD 64
#define CH1 256
#define CH2 512

typedef unsigned short ushort_t;
typedef float f32x4 __attribute__((ext_vector_type(4)));
typedef __bf16 bf16x8 __attribute__((ext_vector_type(8)));
typedef unsigned short u16x8 __attribute__((ext_vector_type(8)));

static __device__ __forceinline__ float leaky(float x) { return x > 0.f ? x : 0.2f * x; }

static __device__ __forceinline__ ushort_t f2bf(float f) {
    union { __hip_bfloat16 h; ushort_t u; } c;
    c.h = __float2bfloat16(f);
    return c.u;
}

static __device__ __forceinline__ float b2f(ushort_t u) {
    union { unsigned int i; float f; } c;
    c.i = ((unsigned int)u) << 16;
    return c.f;
}

// ---------------- CSR build ----------------
__global__ void count_kernel(const int* __restrict__ dst0, const int* __restrict__ ety,
                             int* __restrict__ deg, int* __restrict__ relcnt, int E) {
    int e = blockIdx.x * blockDim.x + threadIdx.x;
    if (e >= E) return;
    int d = dst0[e];
    atomicAdd(&deg[d], 1);
    atomicAdd(&relcnt[d * NREL + ety[e]], 1);
}

// one-pass scan: per-thread serial sum -> wave shfl scan -> t0 combines 16 wave sums
__global__ void __launch_bounds__(1024) scan_kernel(const int* __restrict__ deg,
                                                    int* __restrict__ rowptr, int n) {
    __shared__ int wsum[16];
    __shared__ int wbase[16];
    int t = threadIdx.x;
    int per = (n + 1023) >> 10;
    int start = t * per;
    int end = min(start + per, n);
    int s = 0;
    for (int i = start; i < end; i++) s += deg[i];
    int lane = t & 63, w = t >> 6;
    int v = s;
    for (int o = 1; o < 64; o <<= 1) {
        int u = __shfl_up(v, o, 64);
        if (lane >= o) v += u;
    }
    if (lane == 63) wsum[w] = v;
    __syncthreads();
    if (t == 0) {
        int run = 0;
        for (int i = 0; i < 16; i++) {
            wbase[i] = run;
            run += wsum[i];
        }
        rowptr[n] = run;
    }
    __syncthreads();
    int run = wbase[w] + (v - s);
    for (int i = start; i < end; i++) {
        rowptr[i] = run;
        run += deg[i];
    }
}

__global__ void scatter_kernel(const int* __restrict__ src0, const int* __restrict__ dst0,
                               const int* __restrict__ ety, const int* __restrict__ rowptr,
                               int* __restrict__ fill, int* __restrict__ src_srt,
                               int* __restrict__ ty_srt, int E) {
    int e = blockIdx.x * blockDim.x + threadIdx.x;
    if (e >= E) return;
    int d = dst0[e];
    int pos = rowptr[d] + atomicAdd(&fill[d], 1);
    src_srt[pos] = src0[e];
    ty_srt[pos] = ety[e];
}

// rel_alpha[r][h] = sum_c (rel_emb[r] @ We1)[h*32+c] * att_e1[h][c]
__global__ void rel_alpha_kernel(const float* __restrict__ rel_emb, const float* __restrict__ We1,
                                 const float* __restrict__ att_e1, float* __restrict__ rel_alpha) {
    int t = threadIdx.x;
    if (t >= NREL * NHEAD) return;
    int r = t / NHEAD, h = t % NHEAD;
    float acc = 0.f;
    for (int c = 0; c < HID / NHEAD; c++) {
        float v = 0.f;
        for (int k = 0; k < RD; k++) v += rel_emb[r * RD + k] * We1[k * HID + h * 32 + c];
        acc += v * att_e1[h * 32 + c];
    }
    rel_alpha[r * NHEAD + h] = acc;
}

// W[K][Nc] fp32 -> Wt[Nc][K] bf16
__global__ void transpose_conv(const float* __restrict__ W, ushort_t* __restrict__ Wt,
                               int K, int Nc) {
    int i = blockIdx.x * 256 + threadIdx.x;
    if (i >= K * Nc) return;
    int k = i / Nc, n = i % Nc;
    Wt[n * K + k] = f2bf(W[i]);
}

// ---------------- MFMA bf16 GEMM: C[M,Nout](bf16) = A[M,K] @ Bt[Nout,K]^T ----------------
// 128x128 tile, BK=64, 4 waves, 4x4 16x16x32 fragments/wave. 1-D grid with bijective
// XCD-chunked swizzle (m204) so the NBlk tiles sharing an A-panel land on one XCD's L2.
// C rows [M, Mpad) get stored (zeros via A-guard for AF32; caller pads A for bf16 path).
template <bool AF32>
__global__ void __launch_bounds__(256) gemm_mfma(const float* __restrict__ Af,
                                                 const ushort_t* __restrict__ Ab,
                                                 const ushort_t* __restrict__ Bt,
                                                 ushort_t* __restrict__ C,
                                                 int M, int K, int Nout, int NBlk) {
    __shared__ ushort_t sA[128 * 72];
    __shared__ ushort_t sB[128 * 72];
    int T = gridDim.x;
    int p = blockIdx.x;
    int q = T >> 3, rr8 = T & 7, xc = p & 7, j = p >> 3;
    int l = (xc < rr8 ? xc * (q + 1) : rr8 * (q + 1) + (xc - rr8) * q) + j;
    int m0 = (l / NBlk) * 128;
    int n0 = (l % NBlk) * 128;
    int t = threadIdx.x;
    int w = t >> 6, ln = t & 63;
    int wm = (w >> 1) * 64, wn = (w & 1) * 64;
    int r = t >> 1;  // staging row 0..127
    int hh = t & 1;  // 32-col half
    f32x4 acc[4][4] = {};
    for (int k0 = 0; k0 < K; k0 += 64) {
        {
            u16x8 o[4];
            if (AF32) {
                float4 f[8];
                if (m0 + r < M) {
                    const float4* s4 = reinterpret_cast<const float4*>(
                        Af + (size_t)(m0 + r) * K + k0 + hh * 32);
#pragma unroll
                    for (int i = 0; i < 8; i++) f[i] = s4[i];
                } else {
#pragma unroll
                    for (int i = 0; i < 8; i++) f[i] = make_float4(0.f, 0.f, 0.f, 0.f);
                }
#pragma unroll
                for (int jj = 0; jj < 4; jj++) {
                    o[jj][0] = f2bf(f[2 * jj].x);
                    o[jj][1] = f2bf(f[2 * jj].y);
                    o[jj][2] = f2bf(f[2 * jj].z);
                    o[jj][3] = f2bf(f[2 * jj].w);
                    o[jj][4] = f2bf(f[2 * jj + 1].x);
                    o[jj][5] = f2bf(f[2 * jj + 1].y);
                    o[jj][6] = f2bf(f[2 * jj + 1].z);
                    o[jj][7] = f2bf(f[2 * jj + 1].w);
                }
            } else {
                const u16x8* s8 = reinterpret_cast<const u16x8*>(
                    Ab + (size_t)(m0 + r) * K + k0 + hh * 32);
#pragma unroll
                for (int jj = 0; jj < 4; jj++) o[jj] = s8[jj];
            }
#pragma unroll
            for (int jj = 0; jj < 4; jj++)
                *reinterpret_cast<u16x8*>(&sA[r * 72 + hh * 32 + jj * 8]) = o[jj];
        }
        {
            const u16x8* s8 = reinterpret_cast<const u16x8*>(
                Bt + (size_t)(n0 + r) * K + k0 + hh * 32);
#pragma unroll
            for (int jj = 0; jj < 4; jj++)
                *reinterpret_cast<u16x8*>(&sB[r * 72 + hh * 32 + jj * 8]) = s8[jj];
        }
        __syncthreads();
#pragma unroll
        for (int ks = 0; ks < 2; ks++) {
            bf16x8 af[4], bfr[4];
#pragma unroll
            for (int m = 0; m < 4; m++)
                af[m] = *reinterpret_cast<const bf16x8*>(
                    &sA[(wm + m * 16 + (ln & 15)) * 72 + ks * 32 + (ln >> 4) * 8]);
#pragma unroll
            for (int n = 0; n < 4; n++)
                bfr[n] = *reinterpret_cast<const bf16x8*>(
                    &sB[(wn + n * 16 + (ln & 15)) * 72 + ks * 32 + (ln >> 4) * 8]);
#pragma unroll
            for (int m = 0; m < 4; m++)
#pragma unroll
                for (int n = 0; n < 4; n++)
                    acc[m][n] = __builtin_amdgcn_mfma_f32_16x16x32_bf16(af[m], bfr[n], acc[m][n], 0, 0, 0);
        }
        __syncthreads();
    }
#pragma unroll
    for (int m = 0; m < 4; m++) {
#pragma unroll
        for (int rr = 0; rr < 4; rr++) {
            int row = m0 + wm + m * 16 + (ln >> 4) * 4 + rr;
#pragma unroll
            for (int n = 0; n < 4; n++)
                C[(size_t)row * Nout + n0 + wn + n * 16 + (ln & 15)] = f2bf(acc[m][n][rr]);
        }
    }
}

// ---------------- per-node attention scalars, layer 1 (bf16 h1) ----------------
__global__ void __launch_bounds__(256) alpha1_kernel(const ushort_t* __restrict__ h1b,
                                                     const float* __restrict__ att_s,
                                                     const float* __restrict__ att_d,
                                                     const int* __restrict__ relcnt,
                                                     const int* __restrict__ deg,
                                                     const float* __restrict__ rel_alpha,
                                                     float* __restrict__ als, float* __restrict__ ald,
                                                     float* __restrict__ selfa) {
    int i = blockIdx.x, t = threadIdx.x;
    int h = t >> 5, l = t & 31;
    float v = b2f(h1b[(size_t)i * HID + t]);
    float ps = v * att_s[t], pd = v * att_d[t];
    for (int o = 16; o > 0; o >>= 1) {
        ps += __shfl_xor(ps, o, 32);
        pd += __shfl_xor(pd, o, 32);
    }
    if (l == 0) {
        als[i * NHEAD + h] = ps;
        ald[i * NHEAD + h] = pd;
    }
    if (t < NHEAD) {
        float dv = fmaxf((float)deg[i], 1.0f);
        float acc = 0.f;
        for (int r = 0; r < NREL; r++) acc += (float)relcnt[i * NREL + r] * rel_alpha[r * NHEAD + t];
        selfa[i * NHEAD + t] = acc / dv;
    }
}

// ---------------- fused layer-1 aggregation + bias + LN + ELU (bf16 in/out) ----------------
__global__ void __launch_bounds__(256) node_agg1(
    const ushort_t* __restrict__ h1b, const float* __restrict__ als, const float* __restrict__ ald,
    const float* __restrict__ selfa, const float* __restrict__ rel_alpha,
    const int* __restrict__ rowptr, const int* __restrict__ src_srt, const int* __restrict__ ty_srt,
    const float* __restrict__ b1, const float* __restrict__ g1, const float* __restrict__ beta1,
    ushort_t* __restrict__ out) {
    int i = blockIdx.x, t = threadIdx.x;
    int h = t >> 5, l = t & 31;
    __shared__ float sh_alpha[CH1 * 8];
    __shared__ int sh_src[CH1];
    __shared__ float sh_rel[NREL * NHEAD];
    __shared__ float sh_ald[NHEAD];
    __shared__ float sh_m[NHEAD], sh_s[NHEAD], sh_f[NHEAD];
    __shared__ float sh_red[256];
    if (t < NREL * NHEAD) sh_rel[t] = rel_alpha[t];
    if (t < NHEAD) {
        float a_self = leaky(als[i * NHEAD + t] + ald[i * NHEAD + t] + selfa[i * NHEAD + t]);
        sh_m[t] = a_self;
        sh_s[t] = 1.0f;
        sh_ald[t] = ald[i * NHEAD + t];
    }
    __syncthreads();
    float acc = b2f(h1b[(size_t)i * HID + t]);  // self-loop, weight exp(a_self - m)=1
    int base = rowptr[i];
    int deg = rowptr[i + 1] - base;
    for (int cs = 0; cs < deg; cs += CH1) {
        int c = min(CH1, deg - cs);
        for (int k = t; k < c * 8; k += 256) {
            int e = k >> 3, hh = k & 7;
            int sv = src_srt[base + cs + e];
            int tv = ty_srt[base + cs + e];
            float a = als[sv * NHEAD + hh] + sh_ald[hh] + sh_rel[tv * NHEAD + hh];
            sh_alpha[k] = leaky(a);
            if (hh == 0) sh_src[e] = sv;
        }
        __syncthreads();
        float cm = -1e30f;
        for (int e = l; e < c; e += 32) cm = fmaxf(cm, sh_alpha[e * 8 + h]);
        for (int o = 16; o > 0; o >>= 1) cm = fmaxf(cm, __shfl_xor(cm, o, 32));
        if (l == 0) {
            float mo = sh_m[h];
            float nm = fmaxf(mo, cm);
            sh_f[h] = __expf(mo - nm);
            sh_m[h] = nm;
        }
        __syncthreads();
        float nm = sh_m[h], f = sh_f[h];
        float csum = 0.f;
        for (int e = l; e < c; e += 32) {
            float ww = __expf(sh_alpha[e * 8 + h] - nm);
            sh_alpha[e * 8 + h] = ww;
            csum += ww;
        }
        for (int o = 16; o > 0; o >>= 1) csum += __shfl_xor(csum, o, 32);
        if (l == 0) sh_s[h] = sh_s[h] * f + csum;
        acc *= f;
        __syncthreads();
        // x4-unrolled gather: 4 independent row loads in flight
        int e = 0;
        for (; e + 4 <= c; e += 4) {
            int s0 = sh_src[e], s1 = sh_src[e + 1], s2 = sh_src[e + 2], s3 = sh_src[e + 3];
            float w0 = sh_alpha[e * 8 + h], w1 = sh_alpha[(e + 1) * 8 + h];
            float w2 = sh_alpha[(e + 2) * 8 + h], w3 = sh_alpha[(e + 3) * 8 + h];
            float v0 = b2f(h1b[(size_t)s0 * HID + t]);
            float v1 = b2f(h1b[(size_t)s1 * HID + t]);
            float v2 = b2f(h1b[(size_t)s2 * HID + t]);
            float v3 = b2f(h1b[(size_t)s3 * HID + t]);
            acc += w0 * v0 + w1 * v1 + w2 * v2 + w3 * v3;
        }
        for (; e < c; e++) acc += sh_alpha[e * 8 + h] * b2f(h1b[(size_t)sh_src[e] * HID + t]);
        __syncthreads();
    }
    float s = sh_s[h];
    acc = acc / (s + 1e-16f) + b1[t];
    sh_red[t] = acc;
    __syncthreads();
    for (int o = 128; o > 0; o >>= 1) {
        if (t < o) sh_red[t] += sh_red[t + o];
        __syncthreads();
    }
    float mean = sh_red[0] * (1.f / 256.f);
    __syncthreads();
    float dd = acc - mean;
    sh_red[t] = dd * dd;
    __syncthreads();
    for (int o = 128; o > 0; o >>= 1) {
        if (t < o) sh_red[t] += sh_red[t + o];
        __syncthreads();
    }
    float var = sh_red[0] * (1.f / 256.f);
    float y = dd * rsqrtf(var + 1e-5f) * g1[t] + beta1[t];
    out[(size_t)i * HID + t] = f2bf(y > 0.f ? y : __expf(y) - 1.f);
}

// ---------------- per-node attention scalars, layer 2 (1 head, bf16 h2) ----------------
__global__ void __launch_bounds__(128) alpha2_kernel(const ushort_t* __restrict__ h2b,
                                                     const float* __restrict__ att_s,
                                                     const float* __restrict__ att_d,
                                                     float* __restrict__ als, float* __restrict__ ald) {
    int i = blockIdx.x, t = threadIdx.x;
    float v = b2f(h2b[(size_t)i * OUT_DIM + t]);
    float ps = v * att_s[t], pd = v * att_d[t];
    for (int o = 32; o > 0; o >>= 1) {
        ps += __shfl_xor(ps, o, 64);
        pd += __shfl_xor(pd, o, 64);
    }
    __shared__ float r0[2], r1[2];
    if ((t & 63) == 0) {
        r0[t >> 6] = ps;
        r1[t >> 6] = pd;
    }
    __syncthreads();
    if (t == 0) {
        als[i] = r0[0] + r0[1];
        ald[i] = r1[0] + r1[1];
    }
}

// ---------------- fused layer-2 aggregation + bias + LN ----------------
__global__ void __launch_bounds__(128) node_agg2(const ushort_t* __restrict__ h2b,
                                                 const float* __restrict__ als,
                                                 const float* __restrict__ ald,
                                                 const int* __restrict__ rowptr,
                                                 const int* __restrict__ src_srt,
                                                 const float* __restrict__ b2,
                                                 const float* __restrict__ g2,
                                                 const float* __restrict__ beta2,
                                                 float* __restrict__ out) {
    int i = blockIdx.x, t = threadIdx.x;
    __shared__ float sh_a[CH2];
    __shared__ int sh_src[CH2];
    __shared__ float sh_red[128];
    float aldi = ald[i];
    float aself = leaky(als[i] + aldi);
    float m = aself, s = 1.0f;
    float acc = b2f(h2b[(size_t)i * OUT_DIM + t]);
    int base = rowptr[i];
    int deg = rowptr[i + 1] - base;
    for (int cs = 0; cs < deg; cs += CH2) {
        int c = min(CH2, deg - cs);
        for (int k = t; k < c; k += 128) {
            int sv = src_srt[base + cs + k];
            sh_src[k] = sv;
            sh_a[k] = leaky(als[sv] + aldi);
        }
        __syncthreads();
        float cm = -1e30f;
        for (int e = t; e < c; e += 128) cm = fmaxf(cm, sh_a[e]);
        for (int o = 32; o > 0; o >>= 1) cm = fmaxf(cm, __shfl_xor(cm, o, 64));
        if ((t & 63) == 0) sh_red[t >> 6] = cm;
        __syncthreads();
        cm = fmaxf(sh_red[0], sh_red[1]);
        float newm = fmaxf(m, cm);
        float f = __expf(m - newm);
        float csum = 0.f;
        for (int k = t; k < c; k += 128) {
            float ww = __expf(sh_a[k] - newm);
            sh_a[k] = ww;
            csum += ww;
        }
        for (int o = 32; o > 0; o >>= 1) csum += __shfl_xor(csum, o, 64);
        __syncthreads();
        if ((t & 63) == 0) sh_red[t >> 6] = csum;
        __syncthreads();
        csum = sh_red[0] + sh_red[1];
        s = s * f + csum;
        m = newm;
        acc *= f;
        int e = 0;
        for (; e + 4 <= c; e += 4) {
            int s0 = sh_src[e], s1 = sh_src[e + 1], s2 = sh_src[e + 2], s3 = sh_src[e + 3];
            float w0 = sh_a[e], w1 = sh_a[e + 1], w2 = sh_a[e + 2], w3 = sh_a[e + 3];
            float v0 = b2f(h2b[(size_t)s0 * OUT_DIM + t]);
            float v1 = b2f(h2b[(size_t)s1 * OUT_DIM + t]);
            float v2 = b2f(h2b[(size_t)s2 * OUT_DIM + t]);
            float v3 = b2f(h2b[(size_t)s3 * OUT_DIM + t]);
            acc += w0 * v0 + w1 * v1 + w2 * v2 + w3 * v3;
        }
        for (; e < c; e++) acc += sh_a[e] * b2f(h2b[(size_t)sh_src[e] * OUT_DIM + t]);
        __syncthreads();
    }
    acc = acc / (s + 1e-16f) + b2[t];
    sh_red[t] = acc;
    __syncthreads();
    for (int o = 64; o > 0; o >>= 1) {
        if (t < o) sh_red[t] += sh_red[t + o];
        __syncthreads();
    }
    float mean = sh_red[0] * (1.f / 128.f);
    __syncthreads();
    float dd = acc - mean;
    sh_red[t] = dd * dd;
    __syncthreads();
    for (int o = 64; o > 0; o >>= 1) {
        if (t < o) sh_red[t] += sh_red[t + o];
        __syncthreads();
    }
    float var = sh_red[0] * (1.f / 128.f);
    out[(size_t)i * OUT_DIM + t] = dd * rsqrtf(var + 1e-5f) * g2[t] + beta2[t];
}

extern "C" void kernel_launch(void* const* d_in, const int* in_sizes, int n_in,
                              void* d_out, int out_size, void* d_ws, size_t ws_size,
                              hipStream_t stream) {
    const float* x = (const float*)d_in[0];
    const int* ei = (const int*)d_in[1];
    const int* ety = (const int*)d_in[2];
    const float* rel_emb = (const float*)d_in[3];
    const float* W1 = (const float*)d_in[4];
    const float* att_s1 = (const float*)d_in[5];
    const float* att_d1 = (const float*)d_in[6];
    const float* We1 = (const float*)d_in[7];
    const float* att_e1 = (const float*)d_in[8];
    const float* b1 = (const float*)d_in[9];
    const float* g1 = (const float*)d_in[10];
    const float* beta1 = (const float*)d_in[11];
    const float* W2 = (const float*)d_in[12];
    const float* att_s2 = (const float*)d_in[13];
    const float* att_d2 = (const float*)d_in[14];
    const float* b2 = (const float*)d_in[15];
    const float* g2 = (const float*)d_in[16];
    const float* beta2 = (const float*)d_in[17];

    int N = in_sizes[0] / IN_DIM;
    int E = in_sizes[1] / 2;
    int Mpad = ((N + 127) / 128) * 128;
    const int* src0 = ei;
    const int* dst0 = ei + E;

    char* ws = (char*)d_ws;
    size_t off = 0;
    auto alloc = [&](size_t bytes) -> void* {
        off = (off + 255) & ~(size_t)255;
        void* p = ws + off;
        off += bytes;
        return p;
    };
    int* deg = (int*)alloc((size_t)N * 4);
    int* relcnt = (int*)alloc((size_t)N * NREL * 4);
    int* fill = (int*)alloc((size_t)N * 4);
    int* rowptr = (int*)alloc((size_t)(N + 1) * 4);
    int* src_srt = (int*)alloc((size_t)E * 4);
    int* ty_srt = (int*)alloc((size_t)E * 4);
    float* rel_alpha = (float*)alloc(NREL * NHEAD * 4);
    float* als1 = (float*)alloc((size_t)N * NHEAD * 4);
    float* ald1 = (float*)alloc((size_t)N * NHEAD * 4);
    float* selfa = (float*)alloc((size_t)N * NHEAD * 4);
    float* al2s = (float*)alloc((size_t)N * 4);
    float* al2d = (float*)alloc((size_t)N * 4);
    ushort_t* W1t = (ushort_t*)alloc((size_t)HID * IN_DIM * 2);
    ushort_t* W2t = (ushort_t*)alloc((size_t)OUT_DIM * HID * 2);
    ushort_t* h1b = (ushort_t*)alloc((size_t)Mpad * HID * 2);
    ushort_t* h1pb = (ushort_t*)alloc((size_t)Mpad * HID * 2);
    ushort_t* h2b = h1b;  // h1b dead after node_agg1 -> reuse for layer-2 features

    hipMemsetAsync(deg, 0, (size_t)N * 4, stream);
    hipMemsetAsync(relcnt, 0, (size_t)N * NREL * 4, stream);
    hipMemsetAsync(fill, 0, (size_t)N * 4, stream);
    // pad tail of h1pb: gemm2's A-staging reads rows [N, Mpad)
    hipMemsetAsync(h1pb + (size_t)N * HID, 0, (size_t)(Mpad - N) * HID * 2, stream);

    int eb = (E + 255) / 256;
    count_kernel<<<eb, 256, 0, stream>>>(dst0, ety, deg, relcnt, E);
    scan_kernel<<<1, 1024, 0, stream>>>(deg, rowptr, N);
    scatter_kernel<<<eb, 256, 0, stream>>>(src0, dst0, ety, rowptr, fill, src_srt, ty_srt, E);
    rel_alpha_kernel<<<1, 64, 0, stream>>>(rel_emb, We1, att_e1, rel_alpha);
    transpose_conv<<<(IN_DIM * HID + 255) / 256, 256, 0, stream>>>(W1, W1t, IN_DIM, HID);
    transpose_conv<<<(HID * OUT_DIM + 255) / 256, 256, 0, stream>>>(W2, W2t, HID, OUT_DIM);

    int NB1 = HID / 128;
    int T1 = (Mpad / 128) * NB1;
    gemm_mfma<true><<<T1, 256, 0, stream>>>(x, (const ushort_t*)nullptr, W1t, h1b, N, IN_DIM, HID, NB1);
    alpha1_kernel<<<N, 256, 0, stream>>>(h1b, att_s1, att_d1, relcnt, deg, rel_alpha, als1, ald1, selfa);
    node_agg1<<<N, 256, 0, stream>>>(h1b, als1, ald1, selfa, rel_alpha, rowptr, src_srt, ty_srt,
                                     b1, g1, beta1, h1pb);

    int NB2 = OUT_DIM / 128;
    int T2 = (Mpad / 128) * NB2;
    gemm_mfma<false><<<T2, 256, 0, stream>>>((const float*)nullptr, h1pb, W2t, h2b, N, HID, OUT_DIM, NB2);
    alpha2_kernel<<<N, 128, 0, stream>>>(h2b, att_s2, att_d2, al2s, al2d);
    node_agg2<<<N, 128, 0, stream>>>(h2b, al2s, al2d, rowptr, src_srt, b2, g2, beta2, (float*)d_out);
}

// Round 4
// 517.878 us; speedup vs baseline: 2.2967x; 1.2597x over previous
//
#include <hip/hip_runtime.h>
#include <hip/hip_bf16.h>

#define IN_DIM 768
#define HID 256
#define OUT_DIM 128
#define NHEAD 8
#define NREL 6
#define RD 64

typedef unsigned short ushort_t;
typedef float f32x4 __attribute__((ext_vector_type(4)));
typedef __bf16 bf16x8 __attribute__((ext_vector_type(8)));
typedef unsigned short u16x8 __attribute__((ext_vector_type(8)));
typedef unsigned short u16x4 __attribute__((ext_vector_type(4)));
typedef unsigned short u16x2 __attribute__((ext_vector_type(2)));

static __device__ __forceinline__ float leaky(float x) { return x > 0.f ? x : 0.2f * x; }

static __device__ __forceinline__ ushort_t f2bf(float f) {
    union { __hip_bfloat16 h; ushort_t u; } c;
    c.h = __float2bfloat16(f);
    return c.u;
}

static __device__ __forceinline__ float b2f(ushort_t u) {
    union { unsigned int i; float f; } c;
    c.i = ((unsigned int)u) << 16;
    return c.f;
}

// ---------------- CSR build ----------------
__global__ void count_kernel(const int* __restrict__ dst0, const int* __restrict__ ety,
                             int* __restrict__ deg, int* __restrict__ relcnt, int E) {
    int e = blockIdx.x * blockDim.x + threadIdx.x;
    if (e >= E) return;
    int d = dst0[e];
    atomicAdd(&deg[d], 1);
    atomicAdd(&relcnt[d * NREL + ety[e]], 1);
}

// one-pass scan: per-thread serial sum -> wave shfl scan -> t0 combines 16 wave sums
__global__ void __launch_bounds__(1024) scan_kernel(const int* __restrict__ deg,
                                                    int* __restrict__ rowptr, int n) {
    __shared__ int wsum[16];
    __shared__ int wbase[16];
    int t = threadIdx.x;
    int per = (n + 1023) >> 10;
    int start = t * per;
    int end = min(start + per, n);
    int s = 0;
    for (int i = start; i < end; i++) s += deg[i];
    int lane = t & 63, w = t >> 6;
    int v = s;
    for (int o = 1; o < 64; o <<= 1) {
        int u = __shfl_up(v, o, 64);
        if (lane >= o) v += u;
    }
    if (lane == 63) wsum[w] = v;
    __syncthreads();
    if (t == 0) {
        int run = 0;
        for (int i = 0; i < 16; i++) {
            wbase[i] = run;
            run += wsum[i];
        }
        rowptr[n] = run;
    }
    __syncthreads();
    int run = wbase[w] + (v - s);
    for (int i = start; i < end; i++) {
        rowptr[i] = run;
        run += deg[i];
    }
}

__global__ void scatter_kernel(const int* __restrict__ src0, const int* __restrict__ dst0,
                               const int* __restrict__ ety, const int* __restrict__ rowptr,
                               int* __restrict__ fill, int* __restrict__ src_srt,
                               int* __restrict__ ty_srt, int E) {
    int e = blockIdx.x * blockDim.x + threadIdx.x;
    if (e >= E) return;
    int d = dst0[e];
    int pos = rowptr[d] + atomicAdd(&fill[d], 1);
    src_srt[pos] = src0[e];
    ty_srt[pos] = ety[e];
}

// rel_alpha[r][h] = sum_c (rel_emb[r] @ We1)[h*32+c] * att_e1[h][c]
__global__ void rel_alpha_kernel(const float* __restrict__ rel_emb, const float* __restrict__ We1,
                                 const float* __restrict__ att_e1, float* __restrict__ rel_alpha) {
    int t = threadIdx.x;
    if (t >= NREL * NHEAD) return;
    int r = t / NHEAD, h = t % NHEAD;
    float acc = 0.f;
    for (int c = 0; c < HID / NHEAD; c++) {
        float v = 0.f;
        for (int k = 0; k < RD; k++) v += rel_emb[r * RD + k] * We1[k * HID + h * 32 + c];
        acc += v * att_e1[h * 32 + c];
    }
    rel_alpha[r * NHEAD + h] = acc;
}

// W[K][Nc] fp32 -> Wt[Nc][K] bf16
__global__ void transpose_conv(const float* __restrict__ W, ushort_t* __restrict__ Wt,
                               int K, int Nc) {
    int i = blockIdx.x * 256 + threadIdx.x;
    if (i >= K * Nc) return;
    int k = i / Nc, n = i % Nc;
    Wt[n * K + k] = f2bf(W[i]);
}

// ---------------- MFMA bf16 GEMM: C[M,Nout](bf16) = A[M,K] @ Bt[Nout,K]^T ----------------
template <bool AF32>
__global__ void __launch_bounds__(256) gemm_mfma(const float* __restrict__ Af,
                                                 const ushort_t* __restrict__ Ab,
                                                 const ushort_t* __restrict__ Bt,
                                                 ushort_t* __restrict__ C,
                                                 int M, int K, int Nout, int NBlk) {
    __shared__ ushort_t sA[128 * 72];
    __shared__ ushort_t sB[128 * 72];
    int T = gridDim.x;
    int p = blockIdx.x;
    int q = T >> 3, rr8 = T & 7, xc = p & 7, j = p >> 3;
    int l = (xc < rr8 ? xc * (q + 1) : rr8 * (q + 1) + (xc - rr8) * q) + j;
    int m0 = (l / NBlk) * 128;
    int n0 = (l % NBlk) * 128;
    int t = threadIdx.x;
    int w = t >> 6, ln = t & 63;
    int wm = (w >> 1) * 64, wn = (w & 1) * 64;
    int r = t >> 1;
    int hh = t & 1;
    f32x4 acc[4][4] = {};
    for (int k0 = 0; k0 < K; k0 += 64) {
        {
            u16x8 o[4];
            if (AF32) {
                float4 f[8];
                if (m0 + r < M) {
                    const float4* s4 = reinterpret_cast<const float4*>(
                        Af + (size_t)(m0 + r) * K + k0 + hh * 32);
#pragma unroll
                    for (int i = 0; i < 8; i++) f[i] = s4[i];
                } else {
#pragma unroll
                    for (int i = 0; i < 8; i++) f[i] = make_float4(0.f, 0.f, 0.f, 0.f);
                }
#pragma unroll
                for (int jj = 0; jj < 4; jj++) {
                    o[jj][0] = f2bf(f[2 * jj].x);
                    o[jj][1] = f2bf(f[2 * jj].y);
                    o[jj][2] = f2bf(f[2 * jj].z);
                    o[jj][3] = f2bf(f[2 * jj].w);
                    o[jj][4] = f2bf(f[2 * jj + 1].x);
                    o[jj][5] = f2bf(f[2 * jj + 1].y);
                    o[jj][6] = f2bf(f[2 * jj + 1].z);
                    o[jj][7] = f2bf(f[2 * jj + 1].w);
                }
            } else {
                const u16x8* s8 = reinterpret_cast<const u16x8*>(
                    Ab + (size_t)(m0 + r) * K + k0 + hh * 32);
#pragma unroll
                for (int jj = 0; jj < 4; jj++) o[jj] = s8[jj];
            }
#pragma unroll
            for (int jj = 0; jj < 4; jj++)
                *reinterpret_cast<u16x8*>(&sA[r * 72 + hh * 32 + jj * 8]) = o[jj];
        }
        {
            const u16x8* s8 = reinterpret_cast<const u16x8*>(
                Bt + (size_t)(n0 + r) * K + k0 + hh * 32);
#pragma unroll
            for (int jj = 0; jj < 4; jj++)
                *reinterpret_cast<u16x8*>(&sB[r * 72 + hh * 32 + jj * 8]) = s8[jj];
        }
        __syncthreads();
#pragma unroll
        for (int ks = 0; ks < 2; ks++) {
            bf16x8 af[4], bfr[4];
#pragma unroll
            for (int m = 0; m < 4; m++)
                af[m] = *reinterpret_cast<const bf16x8*>(
                    &sA[(wm + m * 16 + (ln & 15)) * 72 + ks * 32 + (ln >> 4) * 8]);
#pragma unroll
            for (int n = 0; n < 4; n++)
                bfr[n] = *reinterpret_cast<const bf16x8*>(
                    &sB[(wn + n * 16 + (ln & 15)) * 72 + ks * 32 + (ln >> 4) * 8]);
#pragma unroll
            for (int m = 0; m < 4; m++)
#pragma unroll
                for (int n = 0; n < 4; n++)
                    acc[m][n] = __builtin_amdgcn_mfma_f32_16x16x32_bf16(af[m], bfr[n], acc[m][n], 0, 0, 0);
        }
        __syncthreads();
    }
#pragma unroll
    for (int m = 0; m < 4; m++) {
#pragma unroll
        for (int rr = 0; rr < 4; rr++) {
            int row = m0 + wm + m * 16 + (ln >> 4) * 4 + rr;
#pragma unroll
            for (int n = 0; n < 4; n++)
                C[(size_t)row * Nout + n0 + wn + n * 16 + (ln & 15)] = f2bf(acc[m][n][rr]);
        }
    }
}

// ---------------- per-node attention scalars, layer 1 (bf16 h1) ----------------
__global__ void __launch_bounds__(256) alpha1_kernel(const ushort_t* __restrict__ h1b,
                                                     const float* __restrict__ att_s,
                                                     const float* __restrict__ att_d,
                                                     const int* __restrict__ relcnt,
                                                     const int* __restrict__ deg,
                                                     const float* __restrict__ rel_alpha,
                                                     float* __restrict__ als, float* __restrict__ ald,
                                                     float* __restrict__ selfa) {
    int i = blockIdx.x, t = threadIdx.x;
    int h = t >> 5, l = t & 31;
    float v = b2f(h1b[(size_t)i * HID + t]);
    float ps = v * att_s[t], pd = v * att_d[t];
    for (int o = 16; o > 0; o >>= 1) {
        ps += __shfl_xor(ps, o, 32);
        pd += __shfl_xor(pd, o, 32);
    }
    if (l == 0) {
        als[i * NHEAD + h] = ps;
        ald[i * NHEAD + h] = pd;
    }
    if (t < NHEAD) {
        float dv = fmaxf((float)deg[i], 1.0f);
        float acc = 0.f;
        for (int r = 0; r < NREL; r++) acc += (float)relcnt[i * NREL + r] * rel_alpha[r * NHEAD + t];
        selfa[i * NHEAD + t] = acc / dv;
    }
}

// ---------------- fused layer-1 aggregation: ONE WAVE PER NODE, zero barriers ----------------
// lane l: channels 4l..4l+3 (all in head hd=l>>3); u16x4 gather loads (8 B/lane,
// wave reads full 512 B row coalesced); softmax via 8-lane-group shuffles; LN via wave shfl.
__global__ void __launch_bounds__(256) node_agg1(
    const ushort_t* __restrict__ h1b, const float* __restrict__ als, const float* __restrict__ ald,
    const float* __restrict__ selfa, const float* __restrict__ rel_alpha,
    const int* __restrict__ rowptr, const int* __restrict__ src_srt, const int* __restrict__ ty_srt,
    const float* __restrict__ b1, const float* __restrict__ g1, const float* __restrict__ beta1,
    ushort_t* __restrict__ out, int N) {
    __shared__ float sh_rel[NREL * NHEAD];
    __shared__ float sh_aw[4][64 * NHEAD];   // per-wave [edge][head]
    __shared__ unsigned sh_off[4][64];       // per-wave row byte offsets
    int w = threadIdx.x >> 6, l = threadIdx.x & 63;
    if (threadIdx.x < NREL * NHEAD) sh_rel[threadIdx.x] = rel_alpha[threadIdx.x];
    __syncthreads();  // only barrier: publish sh_rel
    int i = blockIdx.x * 4 + w;
    if (i >= N) return;
    int hd = l >> 3;   // head for gather/softmax state
    int sub = l & 7;   // stripe / staging head
    float m = leaky(als[i * NHEAD + hd] + ald[i * NHEAD + hd] + selfa[i * NHEAD + hd]);
    float s = 1.0f;
    float ald_stage = ald[i * NHEAD + sub];
    float acc0, acc1, acc2, acc3;
    {
        u16x4 v = *reinterpret_cast<const u16x4*>(h1b + (size_t)i * HID + 4 * l);
        acc0 = b2f(v[0]); acc1 = b2f(v[1]); acc2 = b2f(v[2]); acc3 = b2f(v[3]);
    }
    int base = rowptr[i];
    int deg = rowptr[i + 1] - base;
    const char* hb = reinterpret_cast<const char*>(h1b);
    for (int cs = 0; cs < deg; cs += 64) {
        int c = min(64, deg - cs);
        // stage alpha: 8 edges/pass, lane handles (edge e = p*8 + l>>3, head sub)
        for (int p = 0; p * 8 < c; p++) {
            int e = p * 8 + (l >> 3);
            if (e < c) {
                int sv = src_srt[base + cs + e];
                int tv = ty_srt[base + cs + e];
                float a = als[sv * NHEAD + sub] + ald_stage + sh_rel[tv * NHEAD + sub];
                sh_aw[w][e * NHEAD + sub] = leaky(a);
                if (sub == 0) sh_off[w][e] = (unsigned)sv * (HID * 2);
            }
        }
        // chunk max per head (lane stripe e ≡ sub mod 8)
        float cm = -1e30f;
        for (int e = sub; e < c; e += 8) cm = fmaxf(cm, sh_aw[w][e * NHEAD + hd]);
        for (int o = 1; o < 8; o <<= 1) cm = fmaxf(cm, __shfl_xor(cm, o, 64));
        float nm = fmaxf(m, cm);
        float f = __expf(m - nm);
        float csum = 0.f;
        for (int e = sub; e < c; e += 8) {
            float ww = __expf(sh_aw[w][e * NHEAD + hd] - nm);
            sh_aw[w][e * NHEAD + hd] = ww;
            csum += ww;
        }
        for (int o = 1; o < 8; o <<= 1) csum += __shfl_xor(csum, o, 64);
        s = s * f + csum;
        m = nm;
        acc0 *= f; acc1 *= f; acc2 *= f; acc3 *= f;
        // gather, 4 rows in flight
        int e = 0;
        for (; e + 4 <= c; e += 4) {
            unsigned o0 = sh_off[w][e], o1 = sh_off[w][e + 1];
            unsigned o2 = sh_off[w][e + 2], o3 = sh_off[w][e + 3];
            float w0 = sh_aw[w][e * NHEAD + hd], w1 = sh_aw[w][(e + 1) * NHEAD + hd];
            float w2 = sh_aw[w][(e + 2) * NHEAD + hd], w3 = sh_aw[w][(e + 3) * NHEAD + hd];
            u16x4 v0 = *reinterpret_cast<const u16x4*>(hb + o0 + 8 * l);
            u16x4 v1 = *reinterpret_cast<const u16x4*>(hb + o1 + 8 * l);
            u16x4 v2 = *reinterpret_cast<const u16x4*>(hb + o2 + 8 * l);
            u16x4 v3 = *reinterpret_cast<const u16x4*>(hb + o3 + 8 * l);
            acc0 += w0 * b2f(v0[0]) + w1 * b2f(v1[0]) + w2 * b2f(v2[0]) + w3 * b2f(v3[0]);
            acc1 += w0 * b2f(v0[1]) + w1 * b2f(v1[1]) + w2 * b2f(v2[1]) + w3 * b2f(v3[1]);
            acc2 += w0 * b2f(v0[2]) + w1 * b2f(v1[2]) + w2 * b2f(v2[2]) + w3 * b2f(v3[2]);
            acc3 += w0 * b2f(v0[3]) + w1 * b2f(v1[3]) + w2 * b2f(v2[3]) + w3 * b2f(v3[3]);
        }
        for (; e < c; e++) {
            unsigned o0 = sh_off[w][e];
            float w0 = sh_aw[w][e * NHEAD + hd];
            u16x4 v0 = *reinterpret_cast<const u16x4*>(hb + o0 + 8 * l);
            acc0 += w0 * b2f(v0[0]); acc1 += w0 * b2f(v0[1]);
            acc2 += w0 * b2f(v0[2]); acc3 += w0 * b2f(v0[3]);
        }
    }
    float inv = 1.0f / (s + 1e-16f);
    float4 bb = *reinterpret_cast<const float4*>(b1 + 4 * l);
    float y0 = acc0 * inv + bb.x, y1 = acc1 * inv + bb.y;
    float y2 = acc2 * inv + bb.z, y3 = acc3 * inv + bb.w;
    float su = y0 + y1 + y2 + y3;
    float sq = y0 * y0 + y1 * y1 + y2 * y2 + y3 * y3;
    for (int o = 1; o < 64; o <<= 1) {
        su += __shfl_xor(su, o, 64);
        sq += __shfl_xor(sq, o, 64);
    }
    float mean = su * (1.f / 256.f);
    float var = sq * (1.f / 256.f) - mean * mean;
    float rstd = rsqrtf(var + 1e-5f);
    float4 gg = *reinterpret_cast<const float4*>(g1 + 4 * l);
    float4 be = *reinterpret_cast<const float4*>(beta1 + 4 * l);
    float z0 = (y0 - mean) * rstd * gg.x + be.x;
    float z1 = (y1 - mean) * rstd * gg.y + be.y;
    float z2 = (y2 - mean) * rstd * gg.z + be.z;
    float z3 = (y3 - mean) * rstd * gg.w + be.w;
    u16x4 ov;
    ov[0] = f2bf(z0 > 0.f ? z0 : __expf(z0) - 1.f);
    ov[1] = f2bf(z1 > 0.f ? z1 : __expf(z1) - 1.f);
    ov[2] = f2bf(z2 > 0.f ? z2 : __expf(z2) - 1.f);
    ov[3] = f2bf(z3 > 0.f ? z3 : __expf(z3) - 1.f);
    *reinterpret_cast<u16x4*>(out + (size_t)i * HID + 4 * l) = ov;
}

// ---------------- per-node attention scalars, layer 2 (1 head, bf16 h2) ----------------
__global__ void __launch_bounds__(128) alpha2_kernel(const ushort_t* __restrict__ h2b,
                                                     const float* __restrict__ att_s,
                                                     const float* __restrict__ att_d,
                                                     float* __restrict__ als, float* __restrict__ ald) {
    int i = blockIdx.x, t = threadIdx.x;
    float v = b2f(h2b[(size_t)i * OUT_DIM + t]);
    float ps = v * att_s[t], pd = v * att_d[t];
    for (int o = 32; o > 0; o >>= 1) {
        ps += __shfl_xor(ps, o, 64);
        pd += __shfl_xor(pd, o, 64);
    }
    __shared__ float r0[2], r1[2];
    if ((t & 63) == 0) {
        r0[t >> 6] = ps;
        r1[t >> 6] = pd;
    }
    __syncthreads();
    if (t == 0) {
        als[i] = r0[0] + r0[1];
        ald[i] = r1[0] + r1[1];
    }
}

// ---------------- fused layer-2 aggregation: ONE WAVE PER NODE ----------------
// lane l: channels 2l, 2l+1; u16x2 loads (4 B/lane, 256 B row coalesced); 1 head.
__global__ void __launch_bounds__(256) node_agg2(const ushort_t* __restrict__ h2b,
                                                 const float* __restrict__ als,
                                                 const float* __restrict__ ald,
                                                 const int* __restrict__ rowptr,
                                                 const int* __restrict__ src_srt,
                                                 const float* __restrict__ b2,
                                                 const float* __restrict__ g2,
                                                 const float* __restrict__ beta2,
                                                 float* __restrict__ out, int N) {
    __shared__ float sh_a[4][64];
    __shared__ unsigned sh_off[4][64];
    int w = threadIdx.x >> 6, l = threadIdx.x & 63;
    int i = blockIdx.x * 4 + w;
    if (i >= N) return;
    float aldi = ald[i];
    float m = leaky(als[i] + aldi);
    float s = 1.0f;
    float acc0, acc1;
    {
        u16x2 v = *reinterpret_cast<const u16x2*>(h2b + (size_t)i * OUT_DIM + 2 * l);
        acc0 = b2f(v[0]); acc1 = b2f(v[1]);
    }
    int base = rowptr[i];
    int deg = rowptr[i + 1] - base;
    const char* hb = reinterpret_cast<const char*>(h2b);
    for (int cs = 0; cs < deg; cs += 64) {
        int c = min(64, deg - cs);
        float a = -1e30f;
        if (l < c) {
            int sv = src_srt[base + cs + l];
            a = leaky(als[sv] + aldi);
            sh_off[w][l] = (unsigned)sv * (OUT_DIM * 2);
        }
        float cm = a;
        for (int o = 1; o < 64; o <<= 1) cm = fmaxf(cm, __shfl_xor(cm, o, 64));
        float nm = fmaxf(m, cm);
        float f = __expf(m - nm);
        float ww = (l < c) ? __expf(a - nm) : 0.f;
        sh_a[w][l] = ww;
        float csum = ww;
        for (int o = 1; o < 64; o <<= 1) csum += __shfl_xor(csum, o, 64);
        s = s * f + csum;
        m = nm;
        acc0 *= f; acc1 *= f;
        int e = 0;
        for (; e + 4 <= c; e += 4) {
            unsigned o0 = sh_off[w][e], o1 = sh_off[w][e + 1];
            unsigned o2 = sh_off[w][e + 2], o3 = sh_off[w][e + 3];
            float w0 = sh_a[w][e], w1 = sh_a[w][e + 1];
            float w2 = sh_a[w][e + 2], w3 = sh_a[w][e + 3];
            u16x2 v0 = *reinterpret_cast<const u16x2*>(hb + o0 + 4 * l);
            u16x2 v1 = *reinterpret_cast<const u16x2*>(hb + o1 + 4 * l);
            u16x2 v2 = *reinterpret_cast<const u16x2*>(hb + o2 + 4 * l);
            u16x2 v3 = *reinterpret_cast<const u16x2*>(hb + o3 + 4 * l);
            acc0 += w0 * b2f(v0[0]) + w1 * b2f(v1[0]) + w2 * b2f(v2[0]) + w3 * b2f(v3[0]);
            acc1 += w0 * b2f(v0[1]) + w1 * b2f(v1[1]) + w2 * b2f(v2[1]) + w3 * b2f(v3[1]);
        }
        for (; e < c; e++) {
            unsigned o0 = sh_off[w][e];
            float w0 = sh_a[w][e];
            u16x2 v0 = *reinterpret_cast<const u16x2*>(hb + o0 + 4 * l);
            acc0 += w0 * b2f(v0[0]); acc1 += w0 * b2f(v0[1]);
        }
    }
    float inv = 1.0f / (s + 1e-16f);
    float2 bb = *reinterpret_cast<const float2*>(b2 + 2 * l);
    float y0 = acc0 * inv + bb.x, y1 = acc1 * inv + bb.y;
    float su = y0 + y1, sq = y0 * y0 + y1 * y1;
    for (int o = 1; o < 64; o <<= 1) {
        su += __shfl_xor(su, o, 64);
        sq += __shfl_xor(sq, o, 64);
    }
    float mean = su * (1.f / 128.f);
    float var = sq * (1.f / 128.f) - mean * mean;
    float rstd = rsqrtf(var + 1e-5f);
    float2 gg = *reinterpret_cast<const float2*>(g2 + 2 * l);
    float2 be = *reinterpret_cast<const float2*>(beta2 + 2 * l);
    float2 ov;
    ov.x = (y0 - mean) * rstd * gg.x + be.x;
    ov.y = (y1 - mean) * rstd * gg.y + be.y;
    *reinterpret_cast<float2*>(out + (size_t)i * OUT_DIM + 2 * l) = ov;
}

extern "C" void kernel_launch(void* const* d_in, const int* in_sizes, int n_in,
                              void* d_out, int out_size, void* d_ws, size_t ws_size,
                              hipStream_t stream) {
    const float* x = (const float*)d_in[0];
    const int* ei = (const int*)d_in[1];
    const int* ety = (const int*)d_in[2];
    const float* rel_emb = (const float*)d_in[3];
    const float* W1 = (const float*)d_in[4];
    const float* att_s1 = (const float*)d_in[5];
    const float* att_d1 = (const float*)d_in[6];
    const float* We1 = (const float*)d_in[7];
    const float* att_e1 = (const float*)d_in[8];
    const float* b1 = (const float*)d_in[9];
    const float* g1 = (const float*)d_in[10];
    const float* beta1 = (const float*)d_in[11];
    const float* W2 = (const float*)d_in[12];
    const float* att_s2 = (const float*)d_in[13];
    const float* att_d2 = (const float*)d_in[14];
    const float* b2 = (const float*)d_in[15];
    const float* g2 = (const float*)d_in[16];
    const float* beta2 = (const float*)d_in[17];

    int N = in_sizes[0] / IN_DIM;
    int E = in_sizes[1] / 2;
    int Mpad = ((N + 127) / 128) * 128;
    const int* src0 = ei;
    const int* dst0 = ei + E;

    char* ws = (char*)d_ws;
    size_t off = 0;
    auto alloc = [&](size_t bytes) -> void* {
        off = (off + 255) & ~(size_t)255;
        void* p = ws + off;
        off += bytes;
        return p;
    };
    int* deg = (int*)alloc((size_t)N * 4);
    int* relcnt = (int*)alloc((size_t)N * NREL * 4);
    int* fill = (int*)alloc((size_t)N * 4);
    int* rowptr = (int*)alloc((size_t)(N + 1) * 4);
    int* src_srt = (int*)alloc((size_t)E * 4);
    int* ty_srt = (int*)alloc((size_t)E * 4);
    float* rel_alpha = (float*)alloc(NREL * NHEAD * 4);
    float* als1 = (float*)alloc((size_t)N * NHEAD * 4);
    float* ald1 = (float*)alloc((size_t)N * NHEAD * 4);
    float* selfa = (float*)alloc((size_t)N * NHEAD * 4);
    float* al2s = (float*)alloc((size_t)N * 4);
    float* al2d = (float*)alloc((size_t)N * 4);
    ushort_t* W1t = (ushort_t*)alloc((size_t)HID * IN_DIM * 2);
    ushort_t* W2t = (ushort_t*)alloc((size_t)OUT_DIM * HID * 2);
    ushort_t* h1b = (ushort_t*)alloc((size_t)Mpad * HID * 2);
    ushort_t* h1pb = (ushort_t*)alloc((size_t)Mpad * HID * 2);
    ushort_t* h2b = h1b;  // h1b dead after node_agg1 -> reuse for layer-2 features

    hipMemsetAsync(deg, 0, (size_t)N * 4, stream);
    hipMemsetAsync(relcnt, 0, (size_t)N * NREL * 4, stream);
    hipMemsetAsync(fill, 0, (size_t)N * 4, stream);
    // pad tail of h1pb: gemm2's A-staging reads rows [N, Mpad)
    hipMemsetAsync(h1pb + (size_t)N * HID, 0, (size_t)(Mpad - N) * HID * 2, stream);

    int eb = (E + 255) / 256;
    count_kernel<<<eb, 256, 0, stream>>>(dst0, ety, deg, relcnt, E);
    scan_kernel<<<1, 1024, 0, stream>>>(deg, rowptr, N);
    scatter_kernel<<<eb, 256, 0, stream>>>(src0, dst0, ety, rowptr, fill, src_srt, ty_srt, E);
    rel_alpha_kernel<<<1, 64, 0, stream>>>(rel_emb, We1, att_e1, rel_alpha);
    transpose_conv<<<(IN_DIM * HID + 255) / 256, 256, 0, stream>>>(W1, W1t, IN_DIM, HID);
    transpose_conv<<<(HID * OUT_DIM + 255) / 256, 256, 0, stream>>>(W2, W2t, HID, OUT_DIM);

    int NB1 = HID / 128;
    int T1 = (Mpad / 128) * NB1;
    gemm_mfma<true><<<T1, 256, 0, stream>>>(x, (const ushort_t*)nullptr, W1t, h1b, N, IN_DIM, HID, NB1);
    alpha1_kernel<<<N, 256, 0, stream>>>(h1b, att_s1, att_d1, relcnt, deg, rel_alpha, als1, ald1, selfa);
    node_agg1<<<(N + 3) / 4, 256, 0, stream>>>(h1b, als1, ald1, selfa, rel_alpha, rowptr, src_srt,
                                               ty_srt, b1, g1, beta1, h1pb, N);

    int NB2 = OUT_DIM / 128;
    int T2 = (Mpad / 128) * NB2;
    gemm_mfma<false><<<T2, 256, 0, stream>>>((const float*)nullptr, h1pb, W2t, h2b, N, HID, OUT_DIM, NB2);
    alpha2_kernel<<<N, 128, 0, stream>>>(h2b, att_s2, att_d2, al2s, al2d);
    node_agg2<<<(N + 3) / 4, 256, 0, stream>>>(h2b, al2s, al2d, rowptr, src_srt, b2, g2, beta2,
                                               (float*)d_out, N);
}

// Round 5
// 504.269 us; speedup vs baseline: 2.3587x; 1.0270x over previous
//
#include <hip/hip_runtime.h>
#include <hip/hip_bf16.h>

#define IN_DIM 768
#define HID 256
#define OUT_DIM 128
#define NHEAD 8
#define NREL 6
#define RD 64

typedef unsigned short ushort_t;
typedef float f32x4 __attribute__((ext_vector_type(4)));
typedef __bf16 bf16x8 __attribute__((ext_vector_type(8)));
typedef unsigned short u16x8 __attribute__((ext_vector_type(8)));
typedef unsigned short u16x4 __attribute__((ext_vector_type(4)));
typedef unsigned short u16x2 __attribute__((ext_vector_type(2)));

static __device__ __forceinline__ float leaky(float x) { return x > 0.f ? x : 0.2f * x; }

static __device__ __forceinline__ ushort_t f2bf(float f) {
    union { __hip_bfloat16 h; ushort_t u; } c;
    c.h = __float2bfloat16(f);
    return c.u;
}

static __device__ __forceinline__ float b2f(ushort_t u) {
    union { unsigned int i; float f; } c;
    c.i = ((unsigned int)u) << 16;
    return c.f;
}

// ---------------- CSR build ----------------
__global__ void count_kernel(const int* __restrict__ dst0, const int* __restrict__ ety,
                             int* __restrict__ deg, int* __restrict__ relcnt, int E) {
    int e = blockIdx.x * blockDim.x + threadIdx.x;
    if (e >= E) return;
    int d = dst0[e];
    atomicAdd(&deg[d], 1);
    atomicAdd(&relcnt[d * NREL + ety[e]], 1);
}

// one-pass scan: per-thread serial sum -> wave shfl scan -> t0 combines 16 wave sums
__global__ void __launch_bounds__(1024) scan_kernel(const int* __restrict__ deg,
                                                    int* __restrict__ rowptr, int n) {
    __shared__ int wsum[16];
    __shared__ int wbase[16];
    int t = threadIdx.x;
    int per = (n + 1023) >> 10;
    int start = t * per;
    int end = min(start + per, n);
    int s = 0;
    for (int i = start; i < end; i++) s += deg[i];
    int lane = t & 63, w = t >> 6;
    int v = s;
    for (int o = 1; o < 64; o <<= 1) {
        int u = __shfl_up(v, o, 64);
        if (lane >= o) v += u;
    }
    if (lane == 63) wsum[w] = v;
    __syncthreads();
    if (t == 0) {
        int run = 0;
        for (int i = 0; i < 16; i++) {
            wbase[i] = run;
            run += wsum[i];
        }
        rowptr[n] = run;
    }
    __syncthreads();
    int run = wbase[w] + (v - s);
    for (int i = start; i < end; i++) {
        rowptr[i] = run;
        run += deg[i];
    }
}

// packs src | (type<<24) into one word (one scattered stream instead of two)
__global__ void scatter_kernel(const int* __restrict__ src0, const int* __restrict__ dst0,
                               const int* __restrict__ ety, const int* __restrict__ rowptr,
                               int* __restrict__ fill, int* __restrict__ src_pk, int E) {
    int e = blockIdx.x * blockDim.x + threadIdx.x;
    if (e >= E) return;
    int d = dst0[e];
    int pos = rowptr[d] + atomicAdd(&fill[d], 1);
    src_pk[pos] = src0[e] | (ety[e] << 24);
}

// rel_alpha[r][h] = sum_c (rel_emb[r] @ We1)[h*32+c] * att_e1[h][c]
__global__ void rel_alpha_kernel(const float* __restrict__ rel_emb, const float* __restrict__ We1,
                                 const float* __restrict__ att_e1, float* __restrict__ rel_alpha) {
    int t = threadIdx.x;
    if (t >= NREL * NHEAD) return;
    int r = t / NHEAD, h = t % NHEAD;
    float acc = 0.f;
    for (int c = 0; c < HID / NHEAD; c++) {
        float v = 0.f;
        for (int k = 0; k < RD; k++) v += rel_emb[r * RD + k] * We1[k * HID + h * 32 + c];
        acc += v * att_e1[h * 32 + c];
    }
    rel_alpha[r * NHEAD + h] = acc;
}

// W[K][Nc] fp32 -> Wt[Nc][K] bf16
__global__ void transpose_conv(const float* __restrict__ W, ushort_t* __restrict__ Wt,
                               int K, int Nc) {
    int i = blockIdx.x * 256 + threadIdx.x;
    if (i >= K * Nc) return;
    int k = i / Nc, n = i % Nc;
    Wt[n * K + k] = f2bf(W[i]);
}

// ---------------- MFMA bf16 GEMM: C[M,Nout](bf16) = A[M,K] @ Bt[Nout,K]^T ----------------
// 128x128 tile, BK=64, 4 waves. 2-phase register-prefetch pipeline (T3 minimum):
// issue next tile's global loads BEFORE computing current LDS tile; regs->LDS after.
template <bool AF32>
__global__ void __launch_bounds__(256) gemm_mfma(const float* __restrict__ Af,
                                                 const ushort_t* __restrict__ Ab,
                                                 const ushort_t* __restrict__ Bt,
                                                 ushort_t* __restrict__ C,
                                                 int M, int K, int Nout, int NBlk) {
    __shared__ ushort_t sA[128 * 72];
    __shared__ ushort_t sB[128 * 72];
    int T = gridDim.x;
    int p = blockIdx.x;
    int q = T >> 3, rr8 = T & 7, xc = p & 7, j = p >> 3;
    int l = (xc < rr8 ? xc * (q + 1) : rr8 * (q + 1) + (xc - rr8) * q) + j;
    int m0 = (l / NBlk) * 128;
    int n0 = (l % NBlk) * 128;
    int t = threadIdx.x;
    int w = t >> 6, ln = t & 63;
    int wm = (w >> 1) * 64, wn = (w & 1) * 64;
    int r = t >> 1;
    int hh = t & 1;

    float4 fa[8];   // AF32 prefetch regs
    u16x8 rab[4];   // bf16-A prefetch regs
    u16x8 rb[4];    // B prefetch regs
    f32x4 acc[4][4] = {};

    bool arow_ok = (m0 + r < M);
    const float4* a4 = reinterpret_cast<const float4*>(Af + (size_t)(m0 + r) * K + hh * 32);
    const u16x8* a8 = reinterpret_cast<const u16x8*>(Ab + (size_t)(m0 + r) * K + hh * 32);
    const u16x8* b8 = reinterpret_cast<const u16x8*>(Bt + (size_t)(n0 + r) * K + hh * 32);

    auto load_tile = [&](int k0) {
        if (AF32) {
            if (arow_ok) {
#pragma unroll
                for (int i = 0; i < 8; i++) fa[i] = a4[(k0 >> 2) + i];
            } else {
#pragma unroll
                for (int i = 0; i < 8; i++) fa[i] = make_float4(0.f, 0.f, 0.f, 0.f);
            }
        } else {
#pragma unroll
            for (int i = 0; i < 4; i++) rab[i] = a8[(k0 >> 3) + i];
        }
#pragma unroll
        for (int i = 0; i < 4; i++) rb[i] = b8[(k0 >> 3) + i];
    };

    auto store_lds = [&]() {
        if (AF32) {
#pragma unroll
            for (int jj = 0; jj < 4; jj++) {
                u16x8 o;
                o[0] = f2bf(fa[2 * jj].x);
                o[1] = f2bf(fa[2 * jj].y);
                o[2] = f2bf(fa[2 * jj].z);
                o[3] = f2bf(fa[2 * jj].w);
                o[4] = f2bf(fa[2 * jj + 1].x);
                o[5] = f2bf(fa[2 * jj + 1].y);
                o[6] = f2bf(fa[2 * jj + 1].z);
                o[7] = f2bf(fa[2 * jj + 1].w);
                *reinterpret_cast<u16x8*>(&sA[r * 72 + hh * 32 + jj * 8]) = o;
            }
        } else {
#pragma unroll
            for (int jj = 0; jj < 4; jj++)
                *reinterpret_cast<u16x8*>(&sA[r * 72 + hh * 32 + jj * 8]) = rab[jj];
        }
#pragma unroll
        for (int jj = 0; jj < 4; jj++)
            *reinterpret_cast<u16x8*>(&sB[r * 72 + hh * 32 + jj * 8]) = rb[jj];
    };

    auto compute = [&]() {
#pragma unroll
        for (int ks = 0; ks < 2; ks++) {
            bf16x8 af[4], bfr[4];
#pragma unroll
            for (int m = 0; m < 4; m++)
                af[m] = *reinterpret_cast<const bf16x8*>(
                    &sA[(wm + m * 16 + (ln & 15)) * 72 + ks * 32 + (ln >> 4) * 8]);
#pragma unroll
            for (int n = 0; n < 4; n++)
                bfr[n] = *reinterpret_cast<const bf16x8*>(
                    &sB[(wn + n * 16 + (ln & 15)) * 72 + ks * 32 + (ln >> 4) * 8]);
#pragma unroll
            for (int m = 0; m < 4; m++)
#pragma unroll
                for (int n = 0; n < 4; n++)
                    acc[m][n] = __builtin_amdgcn_mfma_f32_16x16x32_bf16(af[m], bfr[n], acc[m][n], 0, 0, 0);
        }
    };

    load_tile(0);
    store_lds();
    __syncthreads();
    for (int k0 = 64; k0 < K; k0 += 64) {
        load_tile(k0);   // prefetch next tile into regs (latency hides under compute)
        compute();       // consume current LDS tile
        __syncthreads(); // all waves done reading LDS
        store_lds();     // publish prefetched tile
        __syncthreads(); // LDS ready
    }
    compute();

#pragma unroll
    for (int m = 0; m < 4; m++) {
#pragma unroll
        for (int rr = 0; rr < 4; rr++) {
            int row = m0 + wm + m * 16 + (ln >> 4) * 4 + rr;
#pragma unroll
            for (int n = 0; n < 4; n++)
                C[(size_t)row * Nout + n0 + wn + n * 16 + (ln & 15)] = f2bf(acc[m][n][rr]);
        }
    }
}

// ---------------- per-node attention scalars, layer 1 (bf16 h1) ----------------
__global__ void __launch_bounds__(256) alpha1_kernel(const ushort_t* __restrict__ h1b,
                                                     const float* __restrict__ att_s,
                                                     const float* __restrict__ att_d,
                                                     const int* __restrict__ relcnt,
                                                     const int* __restrict__ deg,
                                                     const float* __restrict__ rel_alpha,
                                                     float* __restrict__ als, float* __restrict__ ald,
                                                     float* __restrict__ selfa) {
    int i = blockIdx.x, t = threadIdx.x;
    int h = t >> 5, l = t & 31;
    float v = b2f(h1b[(size_t)i * HID + t]);
    float ps = v * att_s[t], pd = v * att_d[t];
    for (int o = 16; o > 0; o >>= 1) {
        ps += __shfl_xor(ps, o, 32);
        pd += __shfl_xor(pd, o, 32);
    }
    if (l == 0) {
        als[i * NHEAD + h] = ps;
        ald[i * NHEAD + h] = pd;
    }
    if (t < NHEAD) {
        float dv = fmaxf((float)deg[i], 1.0f);
        float acc = 0.f;
        for (int r = 0; r < NREL; r++) acc += (float)relcnt[i * NREL + r] * rel_alpha[r * NHEAD + t];
        selfa[i * NHEAD + t] = acc / dv;
    }
}

// ---------------- fused layer-1 aggregation: ONE WAVE PER NODE, zero barriers ----------------
__global__ void __launch_bounds__(256) node_agg1(
    const ushort_t* __restrict__ h1b, const float* __restrict__ als, const float* __restrict__ ald,
    const float* __restrict__ selfa, const float* __restrict__ rel_alpha,
    const int* __restrict__ rowptr, const int* __restrict__ src_pk,
    const float* __restrict__ b1, const float* __restrict__ g1, const float* __restrict__ beta1,
    ushort_t* __restrict__ out, int N) {
    __shared__ float sh_rel[NREL * NHEAD];
    __shared__ float sh_aw[4][64 * NHEAD];   // per-wave [edge][head]
    __shared__ unsigned sh_off[4][64];       // per-wave row byte offsets
    int w = threadIdx.x >> 6, l = threadIdx.x & 63;
    if (threadIdx.x < NREL * NHEAD) sh_rel[threadIdx.x] = rel_alpha[threadIdx.x];
    __syncthreads();  // only barrier: publish sh_rel
    int i = blockIdx.x * 4 + w;
    if (i >= N) return;
    int hd = l >> 3;
    int sub = l & 7;
    float m = leaky(als[i * NHEAD + hd] + ald[i * NHEAD + hd] + selfa[i * NHEAD + hd]);
    float s = 1.0f;
    float ald_stage = ald[i * NHEAD + sub];
    float acc0, acc1, acc2, acc3;
    {
        u16x4 v = *reinterpret_cast<const u16x4*>(h1b + (size_t)i * HID + 4 * l);
        acc0 = b2f(v[0]); acc1 = b2f(v[1]); acc2 = b2f(v[2]); acc3 = b2f(v[3]);
    }
    int base = rowptr[i];
    int deg = rowptr[i + 1] - base;
    const char* hb = reinterpret_cast<const char*>(h1b);
    for (int cs = 0; cs < deg; cs += 64) {
        int c = min(64, deg - cs);
        for (int p = 0; p * 8 < c; p++) {
            int e = p * 8 + (l >> 3);
            if (e < c) {
                int pk = src_pk[base + cs + e];
                int sv = pk & 0xFFFFFF;
                int tv = (unsigned)pk >> 24;
                float a = als[sv * NHEAD + sub] + ald_stage + sh_rel[tv * NHEAD + sub];
                sh_aw[w][e * NHEAD + sub] = leaky(a);
                if (sub == 0) sh_off[w][e] = (unsigned)sv * (HID * 2);
            }
        }
        float cm = -1e30f;
        for (int e = sub; e < c; e += 8) cm = fmaxf(cm, sh_aw[w][e * NHEAD + hd]);
        for (int o = 1; o < 8; o <<= 1) cm = fmaxf(cm, __shfl_xor(cm, o, 64));
        float nm = fmaxf(m, cm);
        float f = __expf(m - nm);
        float csum = 0.f;
        for (int e = sub; e < c; e += 8) {
            float ww = __expf(sh_aw[w][e * NHEAD + hd] - nm);
            sh_aw[w][e * NHEAD + hd] = ww;
            csum += ww;
        }
        for (int o = 1; o < 8; o <<= 1) csum += __shfl_xor(csum, o, 64);
        s = s * f + csum;
        m = nm;
        acc0 *= f; acc1 *= f; acc2 *= f; acc3 *= f;
        int e = 0;
        for (; e + 4 <= c; e += 4) {
            unsigned o0 = sh_off[w][e], o1 = sh_off[w][e + 1];
            unsigned o2 = sh_off[w][e + 2], o3 = sh_off[w][e + 3];
            float w0 = sh_aw[w][e * NHEAD + hd], w1 = sh_aw[w][(e + 1) * NHEAD + hd];
            float w2 = sh_aw[w][(e + 2) * NHEAD + hd], w3 = sh_aw[w][(e + 3) * NHEAD + hd];
            u16x4 v0 = *reinterpret_cast<const u16x4*>(hb + o0 + 8 * l);
            u16x4 v1 = *reinterpret_cast<const u16x4*>(hb + o1 + 8 * l);
            u16x4 v2 = *reinterpret_cast<const u16x4*>(hb + o2 + 8 * l);
            u16x4 v3 = *reinterpret_cast<const u16x4*>(hb + o3 + 8 * l);
            acc0 += w0 * b2f(v0[0]) + w1 * b2f(v1[0]) + w2 * b2f(v2[0]) + w3 * b2f(v3[0]);
            acc1 += w0 * b2f(v0[1]) + w1 * b2f(v1[1]) + w2 * b2f(v2[1]) + w3 * b2f(v3[1]);
            acc2 += w0 * b2f(v0[2]) + w1 * b2f(v1[2]) + w2 * b2f(v2[2]) + w3 * b2f(v3[2]);
            acc3 += w0 * b2f(v0[3]) + w1 * b2f(v1[3]) + w2 * b2f(v2[3]) + w3 * b2f(v3[3]);
        }
        for (; e < c; e++) {
            unsigned o0 = sh_off[w][e];
            float w0 = sh_aw[w][e * NHEAD + hd];
            u16x4 v0 = *reinterpret_cast<const u16x4*>(hb + o0 + 8 * l);
            acc0 += w0 * b2f(v0[0]); acc1 += w0 * b2f(v0[1]);
            acc2 += w0 * b2f(v0[2]); acc3 += w0 * b2f(v0[3]);
        }
    }
    float inv = 1.0f / (s + 1e-16f);
    float4 bb = *reinterpret_cast<const float4*>(b1 + 4 * l);
    float y0 = acc0 * inv + bb.x, y1 = acc1 * inv + bb.y;
    float y2 = acc2 * inv + bb.z, y3 = acc3 * inv + bb.w;
    float su = y0 + y1 + y2 + y3;
    float sq = y0 * y0 + y1 * y1 + y2 * y2 + y3 * y3;
    for (int o = 1; o < 64; o <<= 1) {
        su += __shfl_xor(su, o, 64);
        sq += __shfl_xor(sq, o, 64);
    }
    float mean = su * (1.f / 256.f);
    float var = sq * (1.f / 256.f) - mean * mean;
    float rstd = rsqrtf(var + 1e-5f);
    float4 gg = *reinterpret_cast<const float4*>(g1 + 4 * l);
    float4 be = *reinterpret_cast<const float4*>(beta1 + 4 * l);
    float z0 = (y0 - mean) * rstd * gg.x + be.x;
    float z1 = (y1 - mean) * rstd * gg.y + be.y;
    float z2 = (y2 - mean) * rstd * gg.z + be.z;
    float z3 = (y3 - mean) * rstd * gg.w + be.w;
    u16x4 ov;
    ov[0] = f2bf(z0 > 0.f ? z0 : __expf(z0) - 1.f);
    ov[1] = f2bf(z1 > 0.f ? z1 : __expf(z1) - 1.f);
    ov[2] = f2bf(z2 > 0.f ? z2 : __expf(z2) - 1.f);
    ov[3] = f2bf(z3 > 0.f ? z3 : __expf(z3) - 1.f);
    *reinterpret_cast<u16x4*>(out + (size_t)i * HID + 4 * l) = ov;
}

// ---------------- per-node attention scalars, layer 2 (1 head, bf16 h2) ----------------
__global__ void __launch_bounds__(128) alpha2_kernel(const ushort_t* __restrict__ h2b,
                                                     const float* __restrict__ att_s,
                                                     const float* __restrict__ att_d,
                                                     float* __restrict__ als, float* __restrict__ ald) {
    int i = blockIdx.x, t = threadIdx.x;
    float v = b2f(h2b[(size_t)i * OUT_DIM + t]);
    float ps = v * att_s[t], pd = v * att_d[t];
    for (int o = 32; o > 0; o >>= 1) {
        ps += __shfl_xor(ps, o, 64);
        pd += __shfl_xor(pd, o, 64);
    }
    __shared__ float r0[2], r1[2];
    if ((t & 63) == 0) {
        r0[t >> 6] = ps;
        r1[t >> 6] = pd;
    }
    __syncthreads();
    if (t == 0) {
        als[i] = r0[0] + r0[1];
        ald[i] = r1[0] + r1[1];
    }
}

// ---------------- fused layer-2 aggregation: ONE WAVE PER NODE ----------------
__global__ void __launch_bounds__(256) node_agg2(const ushort_t* __restrict__ h2b,
                                                 const float* __restrict__ als,
                                                 const float* __restrict__ ald,
                                                 const int* __restrict__ rowptr,
                                                 const int* __restrict__ src_pk,
                                                 const float* __restrict__ b2,
                                                 const float* __restrict__ g2,
                                                 const float* __restrict__ beta2,
                                                 float* __restrict__ out, int N) {
    __shared__ float sh_a[4][64];
    __shared__ unsigned sh_off[4][64];
    int w = threadIdx.x >> 6, l = threadIdx.x & 63;
    int i = blockIdx.x * 4 + w;
    if (i >= N) return;
    float aldi = ald[i];
    float m = leaky(als[i] + aldi);
    float s = 1.0f;
    float acc0, acc1;
    {
        u16x2 v = *reinterpret_cast<const u16x2*>(h2b + (size_t)i * OUT_DIM + 2 * l);
        acc0 = b2f(v[0]); acc1 = b2f(v[1]);
    }
    int base = rowptr[i];
    int deg = rowptr[i + 1] - base;
    const char* hb = reinterpret_cast<const char*>(h2b);
    for (int cs = 0; cs < deg; cs += 64) {
        int c = min(64, deg - cs);
        float a = -1e30f;
        if (l < c) {
            int sv = src_pk[base + cs + l] & 0xFFFFFF;
            a = leaky(als[sv] + aldi);
            sh_off[w][l] = (unsigned)sv * (OUT_DIM * 2);
        }
        float cm = a;
        for (int o = 1; o < 64; o <<= 1) cm = fmaxf(cm, __shfl_xor(cm, o, 64));
        float nm = fmaxf(m, cm);
        float f = __expf(m - nm);
        float ww = (l < c) ? __expf(a - nm) : 0.f;
        sh_a[w][l] = ww;
        float csum = ww;
        for (int o = 1; o < 64; o <<= 1) csum += __shfl_xor(csum, o, 64);
        s = s * f + csum;
        m = nm;
        acc0 *= f; acc1 *= f;
        int e = 0;
        for (; e + 4 <= c; e += 4) {
            unsigned o0 = sh_off[w][e], o1 = sh_off[w][e + 1];
            unsigned o2 = sh_off[w][e + 2], o3 = sh_off[w][e + 3];
            float w0 = sh_a[w][e], w1 = sh_a[w][e + 1];
            float w2 = sh_a[w][e + 2], w3 = sh_a[w][e + 3];
            u16x2 v0 = *reinterpret_cast<const u16x2*>(hb + o0 + 4 * l);
            u16x2 v1 = *reinterpret_cast<const u16x2*>(hb + o1 + 4 * l);
            u16x2 v2 = *reinterpret_cast<const u16x2*>(hb + o2 + 4 * l);
            u16x2 v3 = *reinterpret_cast<const u16x2*>(hb + o3 + 4 * l);
            acc0 += w0 * b2f(v0[0]) + w1 * b2f(v1[0]) + w2 * b2f(v2[0]) + w3 * b2f(v3[0]);
            acc1 += w0 * b2f(v0[1]) + w1 * b2f(v1[1]) + w2 * b2f(v2[1]) + w3 * b2f(v3[1]);
        }
        for (; e < c; e++) {
            unsigned o0 = sh_off[w][e];
            float w0 = sh_a[w][e];
            u16x2 v0 = *reinterpret_cast<const u16x2*>(hb + o0 + 4 * l);
            acc0 += w0 * b2f(v0[0]); acc1 += w0 * b2f(v0[1]);
        }
    }
    float inv = 1.0f / (s + 1e-16f);
    float2 bb = *reinterpret_cast<const float2*>(b2 + 2 * l);
    float y0 = acc0 * inv + bb.x, y1 = acc1 * inv + bb.y;
    float su = y0 + y1, sq = y0 * y0 + y1 * y1;
    for (int o = 1; o < 64; o <<= 1) {
        su += __shfl_xor(su, o, 64);
        sq += __shfl_xor(sq, o, 64);
    }
    float mean = su * (1.f / 128.f);
    float var = sq * (1.f / 128.f) - mean * mean;
    float rstd = rsqrtf(var + 1e-5f);
    float2 gg = *reinterpret_cast<const float2*>(g2 + 2 * l);
    float2 be = *reinterpret_cast<const float2*>(beta2 + 2 * l);
    float2 ov;
    ov.x = (y0 - mean) * rstd * gg.x + be.x;
    ov.y = (y1 - mean) * rstd * gg.y + be.y;
    *reinterpret_cast<float2*>(out + (size_t)i * OUT_DIM + 2 * l) = ov;
}

extern "C" void kernel_launch(void* const* d_in, const int* in_sizes, int n_in,
                              void* d_out, int out_size, void* d_ws, size_t ws_size,
                              hipStream_t stream) {
    const float* x = (const float*)d_in[0];
    const int* ei = (const int*)d_in[1];
    const int* ety = (const int*)d_in[2];
    const float* rel_emb = (const float*)d_in[3];
    const float* W1 = (const float*)d_in[4];
    const float* att_s1 = (const float*)d_in[5];
    const float* att_d1 = (const float*)d_in[6];
    const float* We1 = (const float*)d_in[7];
    const float* att_e1 = (const float*)d_in[8];
    const float* b1 = (const float*)d_in[9];
    const float* g1 = (const float*)d_in[10];
    const float* beta1 = (const float*)d_in[11];
    const float* W2 = (const float*)d_in[12];
    const float* att_s2 = (const float*)d_in[13];
    const float* att_d2 = (const float*)d_in[14];
    const float* b2 = (const float*)d_in[15];
    const float* g2 = (const float*)d_in[16];
    const float* beta2 = (const float*)d_in[17];

    int N = in_sizes[0] / IN_DIM;
    int E = in_sizes[1] / 2;
    int Mpad = ((N + 127) / 128) * 128;
    const int* src0 = ei;
    const int* dst0 = ei + E;

    char* ws = (char*)d_ws;
    size_t off = 0;
    auto alloc = [&](size_t bytes) -> void* {
        off = (off + 255) & ~(size_t)255;
        void* p = ws + off;
        off += bytes;
        return p;
    };
    int* deg = (int*)alloc((size_t)N * 4);
    int* relcnt = (int*)alloc((size_t)N * NREL * 4);
    int* fill = (int*)alloc((size_t)N * 4);
    int* rowptr = (int*)alloc((size_t)(N + 1) * 4);
    int* src_pk = (int*)alloc((size_t)E * 4);
    float* rel_alpha = (float*)alloc(NREL * NHEAD * 4);
    float* als1 = (float*)alloc((size_t)N * NHEAD * 4);
    float* ald1 = (float*)alloc((size_t)N * NHEAD * 4);
    float* selfa = (float*)alloc((size_t)N * NHEAD * 4);
    float* al2s = (float*)alloc((size_t)N * 4);
    float* al2d = (float*)alloc((size_t)N * 4);
    ushort_t* W1t = (ushort_t*)alloc((size_t)HID * IN_DIM * 2);
    ushort_t* W2t = (ushort_t*)alloc((size_t)OUT_DIM * HID * 2);
    ushort_t* h1b = (ushort_t*)alloc((size_t)Mpad * HID * 2);
    ushort_t* h1pb = (ushort_t*)alloc((size_t)Mpad * HID * 2);
    ushort_t* h2b = h1b;  // h1b dead after node_agg1 -> reuse for layer-2 features

    hipMemsetAsync(deg, 0, (size_t)N * 4, stream);
    hipMemsetAsync(relcnt, 0, (size_t)N * NREL * 4, stream);
    hipMemsetAsync(fill, 0, (size_t)N * 4, stream);
    // pad tail of h1pb: gemm2's A-staging reads rows [N, Mpad)
    hipMemsetAsync(h1pb + (size_t)N * HID, 0, (size_t)(Mpad - N) * HID * 2, stream);

    int eb = (E + 255) / 256;
    count_kernel<<<eb, 256, 0, stream>>>(dst0, ety, deg, relcnt, E);
    scan_kernel<<<1, 1024, 0, stream>>>(deg, rowptr, N);
    scatter_kernel<<<eb, 256, 0, stream>>>(src0, dst0, ety, rowptr, fill, src_pk, E);
    rel_alpha_kernel<<<1, 64, 0, stream>>>(rel_emb, We1, att_e1, rel_alpha);
    transpose_conv<<<(IN_DIM * HID + 255) / 256, 256, 0, stream>>>(W1, W1t, IN_DIM, HID);
    transpose_conv<<<(HID * OUT_DIM + 255) / 256, 256, 0, stream>>>(W2, W2t, HID, OUT_DIM);

    int NB1 = HID / 128;
    int T1 = (Mpad / 128) * NB1;
    gemm_mfma<true><<<T1, 256, 0, stream>>>(x, (const ushort_t*)nullptr, W1t, h1b, N, IN_DIM, HID, NB1);
    alpha1_kernel<<<N, 256, 0, stream>>>(h1b, att_s1, att_d1, relcnt, deg, rel_alpha, als1, ald1, selfa);
    node_agg1<<<(N + 3) / 4, 256, 0, stream>>>(h1b, als1, ald1, selfa, rel_alpha, rowptr, src_pk,
                                               b1, g1, beta1, h1pb, N);

    int NB2 = OUT_DIM / 128;
    int T2 = (Mpad / 128) * NB2;
    gemm_mfma<false><<<T2, 256, 0, stream>>>((const float*)nullptr, h1pb, W2t, h2b, N, HID, OUT_DIM, NB2);
    alpha2_kernel<<<N, 128, 0, stream>>>(h2b, att_s2, att_d2, al2s, al2d);
    node_agg2<<<(N + 3) / 4, 256, 0, stream>>>(h2b, al2s, al2d, rowptr, src_pk, b2, g2, beta2,
                                               (float*)d_out, N);
}